// Round 6
// baseline (668.377 us; speedup 1.0000x reference)
//
#include <hip/hip_runtime.h>

// LGConv: out = D^{-1/2} A D^{-1/2} x
// x: f32 [N, 64]; edge_index: int32 on device (harness downcasts int64), [2, E]
//
// Pipeline (all global writes sequential; random-scatter only inside LDS):
//  K1 bin_kernel:   per 4096-edge tile, LDS count/scan/reorder by dst-bin,
//                   flush records {dst,src} as one sequential 32KB write +
//                   per-tile bin-offset directory. No global atomics.
//  K2 deg_kernel2:  per bin, LDS degree histogram via dir runs -> dis slice.
//  K3 gather3:      per bin, LDS-accumulated 391x64 out tile; records in any
//                   order (LDS f32 atomics) -> exact CSR never materialized.

#define DFEAT 64
#define BIN_W 391          // nodes per bin; NB = ceil(N/BIN_W) must be <= 256
#define TILE 4096          // edges per K1 block
#define K1_THREADS 256
#define EPT (TILE / K1_THREADS)   // 16
#define DIRW 257

typedef unsigned long long u64;

// ---------------- K1: LDS-reordered binning ----------------
__global__ __launch_bounds__(K1_THREADS)
void bin_kernel(const int* __restrict__ src, const int* __restrict__ dst,
                u64* __restrict__ records, int* __restrict__ dir,
                int E, int N) {
    __shared__ int cnt[256];
    __shared__ int off[DIRW];
    __shared__ int rnk[256];
    __shared__ u64 buf[TILE];

    const int t    = blockIdx.x;
    const int base = t * TILE;
    const int tid  = threadIdx.x;

    cnt[tid] = 0;
    rnk[tid] = 0;
    __syncthreads();

    // phase A: count (also validates both indices)
    int myb[EPT];
    #pragma unroll
    for (int i = 0; i < EPT; ++i) {
        int e = base + tid + i * K1_THREADS;
        int b = -1;
        if (e < E) {
            unsigned d = (unsigned)dst[e];
            unsigned s = (unsigned)src[e];
            if (d < (unsigned)N && s < (unsigned)N) b = (int)(d / BIN_W);
        }
        myb[i] = b;
        if (b >= 0) atomicAdd(&cnt[b], 1);
    }
    __syncthreads();

    // phase B: exclusive scan of cnt -> off, off[256] = total
    int v = cnt[tid];
    off[tid] = v;
    __syncthreads();
    for (int d = 1; d < 256; d <<= 1) {
        int add = (tid >= d) ? off[tid - d] : 0;
        __syncthreads();
        off[tid] += add;
        __syncthreads();
    }
    int incl = off[tid];
    __syncthreads();
    off[tid] = incl - v;
    if (tid == 255) off[256] = incl;
    __syncthreads();

    // directory row (coalesced)
    dir[t * DIRW + tid] = off[tid];
    if (tid == 0) dir[t * DIRW + 256] = off[256];

    // phase C: place records into LDS at binned positions
    #pragma unroll
    for (int i = 0; i < EPT; ++i) {
        int b = myb[i];
        if (b >= 0) {
            int e = base + tid + i * K1_THREADS;
            unsigned s = (unsigned)src[e];
            unsigned d = (unsigned)dst[e];
            int r = atomicAdd(&rnk[b], 1);
            buf[off[b] + r] = ((u64)d << 32) | (u64)s;
        }
    }
    __syncthreads();

    // phase D: sequential coalesced flush of the whole tile
    int total = off[256];
    for (int i = tid; i < total; i += K1_THREADS)
        records[(size_t)base + i] = buf[i];
}

// ---------------- K2: per-bin degree histogram -> dis ----------------
__global__ __launch_bounds__(256)
void deg_kernel2(const u64* __restrict__ records, const int* __restrict__ dir,
                 float* __restrict__ dis, int N, int NT) {
    __shared__ int deg[BIN_W];
    const int b  = blockIdx.x;
    const int lo = b * BIN_W;
    const int hi = min(lo + BIN_W, N);
    const int nodes = hi - lo;
    const int tid = threadIdx.x;

    for (int i = tid; i < nodes; i += 256) deg[i] = 0;
    __syncthreads();

    const int wave = tid >> 6, lane = tid & 63;
    for (int t = wave; t < NT; t += 4) {
        int s = dir[t * DIRW + b];
        int e = dir[t * DIRW + b + 1];
        int gbase = t * TILE;
        for (int k = s + lane; k < e; k += 64) {
            u64 rec = records[gbase + k];
            int d = (int)(rec >> 32);
            atomicAdd(&deg[d - lo], 1);
        }
    }
    __syncthreads();

    for (int i = tid; i < nodes; i += 256) {
        int c = deg[i];
        dis[lo + i] = (c > 0) ? rsqrtf((float)c) : 0.0f;
    }
}

// ---------------- K3: per-bin LDS-accumulated gather ----------------
#define K3_THREADS 1024
__global__ __launch_bounds__(K3_THREADS)
void gather3_kernel(const float* __restrict__ x,
                    const u64* __restrict__ records,
                    const int* __restrict__ dir,
                    const float* __restrict__ dis,
                    float* __restrict__ out, int N, int NT) {
    __shared__ float tile[BIN_W * DFEAT];   // ~100KB
    const int b  = blockIdx.x;
    const int lo = b * BIN_W;
    const int hi = min(lo + BIN_W, N);
    const int nodes = hi - lo;
    const int tid = threadIdx.x;

    for (int i = tid; i < nodes * DFEAT; i += K3_THREADS) tile[i] = 0.0f;
    __syncthreads();

    const int wave = tid >> 6, lane = tid & 63;
    for (int t = wave; t < NT; t += (K3_THREADS / 64)) {
        int s = dir[t * DIRW + b];
        int e = dir[t * DIRW + b + 1];
        int gbase = t * TILE;
        for (int k0 = s; k0 < e; k0 += 64) {
            int L = min(64, e - k0);
            int mysrc = 0, mydst = 0;
            float w = 0.0f;
            if (lane < L) {
                u64 rec = records[gbase + k0 + lane];
                mysrc = (int)(unsigned)rec;
                mydst = (int)(rec >> 32);
                w = dis[mysrc] * dis[mydst];
            }
            int j = 0;
            for (; j + 3 < L; j += 4) {
                int s0 = __shfl(mysrc, j);     int d0 = __shfl(mydst, j);     float w0 = __shfl(w, j);
                int s1 = __shfl(mysrc, j + 1); int d1 = __shfl(mydst, j + 1); float w1 = __shfl(w, j + 1);
                int s2 = __shfl(mysrc, j + 2); int d2 = __shfl(mydst, j + 2); float w2 = __shfl(w, j + 2);
                int s3 = __shfl(mysrc, j + 3); int d3 = __shfl(mydst, j + 3); float w3 = __shfl(w, j + 3);
                float v0 = x[(size_t)s0 * DFEAT + lane];
                float v1 = x[(size_t)s1 * DFEAT + lane];
                float v2 = x[(size_t)s2 * DFEAT + lane];
                float v3 = x[(size_t)s3 * DFEAT + lane];
                atomicAdd(&tile[(d0 - lo) * DFEAT + lane], v0 * w0);
                atomicAdd(&tile[(d1 - lo) * DFEAT + lane], v1 * w1);
                atomicAdd(&tile[(d2 - lo) * DFEAT + lane], v2 * w2);
                atomicAdd(&tile[(d3 - lo) * DFEAT + lane], v3 * w3);
            }
            for (; j < L; ++j) {
                int s0 = __shfl(mysrc, j); int d0 = __shfl(mydst, j); float w0 = __shfl(w, j);
                float v0 = x[(size_t)s0 * DFEAT + lane];
                atomicAdd(&tile[(d0 - lo) * DFEAT + lane], v0 * w0);
            }
        }
    }
    __syncthreads();

    // sequential float4 flush
    float4* o4 = (float4*)(out + (size_t)lo * DFEAT);
    const float4* t4 = (const float4*)tile;
    for (int i = tid; i < nodes * (DFEAT / 4); i += K3_THREADS)
        o4[i] = t4[i];
}

// ---------------- fallback (atomic scatter) if ws too small ----------------
__global__ void fb_deg_kernel(const int* __restrict__ dst,
                              float* __restrict__ deg, int E, int N) {
    int e = blockIdx.x * blockDim.x + threadIdx.x;
    if (e < E) {
        unsigned d = (unsigned)dst[e];
        if (d < (unsigned)N) unsafeAtomicAdd(&deg[d], 1.0f);
    }
}
__global__ void fb_dis_kernel(float* __restrict__ deg, int N) {
    int i = blockIdx.x * blockDim.x + threadIdx.x;
    if (i < N) {
        float d = deg[i];
        deg[i] = (d > 0.0f) ? rsqrtf(d) : 0.0f;
    }
}
__global__ void fb_scatter_kernel(const float* __restrict__ x,
                                  const int* __restrict__ src,
                                  const int* __restrict__ dst,
                                  const float* __restrict__ dis,
                                  float* __restrict__ out, int E, int N) {
    long long t = (long long)blockIdx.x * blockDim.x + threadIdx.x;
    int e = (int)(t >> 4);
    int c = (int)(t & 15);
    if (e >= E) return;
    unsigned s = (unsigned)src[e];
    unsigned d = (unsigned)dst[e];
    if (s >= (unsigned)N || d >= (unsigned)N) return;
    float norm = dis[s] * dis[d];
    const float4 v = *reinterpret_cast<const float4*>(x + (size_t)s * DFEAT + c * 4);
    float* o = out + (size_t)d * DFEAT + c * 4;
    unsafeAtomicAdd(o + 0, v.x * norm);
    unsafeAtomicAdd(o + 1, v.y * norm);
    unsafeAtomicAdd(o + 2, v.z * norm);
    unsafeAtomicAdd(o + 3, v.w * norm);
}

extern "C" void kernel_launch(void* const* d_in, const int* in_sizes, int n_in,
                              void* d_out, int out_size, void* d_ws, size_t ws_size,
                              hipStream_t stream) {
    const float* x  = (const float*)d_in[0];
    const int*   ei = (const int*)d_in[1];   // harness delivers integer inputs as int32

    const int N = in_sizes[0] / DFEAT;        // 100000
    const int E = in_sizes[1] / 2;            // 1600000
    const int* src = ei;                      // row 0
    const int* dst = ei + E;                  // row 1

    float* out = (float*)d_out;

    const int NB = (N + BIN_W - 1) / BIN_W;   // bins (256 for N=100000)
    const int NT = (E + TILE - 1) / TILE;     // tiles (391 for E=1.6M)

    // workspace layout
    char* base = (char*)d_ws;
    size_t off = 0;
    u64*   records = (u64*)(base + off);   off += (size_t)NT * TILE * 8;
    int*   dir     = (int*)(base + off);   off += (size_t)NT * DIRW * 4;
    float* dis     = (float*)(base + off); off += (size_t)N * 4;

    const bool ok = (off <= ws_size) && (NB <= 256);

    if (ok) {
        bin_kernel<<<NT, K1_THREADS, 0, stream>>>(src, dst, records, dir, E, N);
        deg_kernel2<<<NB, 256, 0, stream>>>(records, dir, dis, N, NT);
        gather3_kernel<<<NB, K3_THREADS, 0, stream>>>(x, records, dir, dis, out, N, NT);
    } else {
        // fallback: atomic scatter (needs only N floats of ws)
        float* deg = (float*)d_ws;
        hipMemsetAsync(deg, 0, (size_t)N * 4, stream);
        hipMemsetAsync(out, 0, (size_t)out_size * 4, stream);
        int eb = (E + 255) / 256;
        fb_deg_kernel<<<eb, 256, 0, stream>>>(dst, deg, E, N);
        int nb = (N + 255) / 256;
        fb_dis_kernel<<<nb, 256, 0, stream>>>(deg, N);
        long long total = (long long)E * 16;
        int sb = (int)((total + 255) / 256);
        fb_scatter_kernel<<<sb, 256, 0, stream>>>(x, src, dst, deg, out, E, N);
    }
}

// Round 7
// 224.749 us; speedup vs baseline: 2.9739x; 2.9739x over previous
//
#include <hip/hip_runtime.h>

// LGConv: out = D^{-1/2} A D^{-1/2} x
// x: f32 [N, 64]; edge_index: int32 on device (harness downcasts int64), [2, E]
//
// Pipeline:
//  K1 bin_kernel: per 4096-edge tile, LDS count/scan/reorder by dst-bin (256
//     bins of BIN_W nodes), sequential flush of {dst,src} records + per-tile
//     directory + per-bin totals. No random global writes.
//  K2 scan_bins: exclusive scan of bin totals -> bin_base, row_ptr[N].
//  K3 csr_build: one block per bin: LDS histogram over the bin's records
//     (via dir runs) -> dis slice + row_ptr slice; second pass scatters
//     csr_src into the bin's private ~25KB window (L2-merged writeback).
//  K4 gather: one wave per dst node, lane = feature dim; exact CSR; unroll 4.

#define DFEAT 64
#define BIN_W 391          // nodes per bin; NB = ceil(N/BIN_W) must be <= 256
#define TILE 4096          // edges per K1 block
#define K1_THREADS 256
#define EPT (TILE / K1_THREADS)   // 16
#define DIRW 257

typedef unsigned long long u64;

// ---------------- K1: LDS-reordered binning ----------------
__global__ __launch_bounds__(K1_THREADS)
void bin_kernel(const int* __restrict__ src, const int* __restrict__ dst,
                u64* __restrict__ records, int* __restrict__ dir,
                int* __restrict__ bin_cnt, int E, int N) {
    __shared__ int cnt[256];
    __shared__ int off[DIRW];
    __shared__ int rnk[256];
    __shared__ u64 buf[TILE];

    const int t    = blockIdx.x;
    const int base = t * TILE;
    const int tid  = threadIdx.x;

    cnt[tid] = 0;
    rnk[tid] = 0;
    __syncthreads();

    // phase A: load + count (validates indices; keep records in regs)
    u64 rec[EPT];
    int myb[EPT];
    #pragma unroll
    for (int i = 0; i < EPT; ++i) {
        int e = base + tid + i * K1_THREADS;
        int b = -1;
        u64 r = 0;
        if (e < E) {
            unsigned d = (unsigned)dst[e];
            unsigned s = (unsigned)src[e];
            if (d < (unsigned)N && s < (unsigned)N) {
                b = (int)(d / BIN_W);
                r = ((u64)d << 32) | (u64)s;
            }
        }
        myb[i] = b;
        rec[i] = r;
        if (b >= 0) atomicAdd(&cnt[b], 1);
    }
    __syncthreads();

    // phase B: exclusive scan of cnt -> off
    int v = cnt[tid];
    off[tid] = v;
    __syncthreads();
    for (int d = 1; d < 256; d <<= 1) {
        int add = (tid >= d) ? off[tid - d] : 0;
        __syncthreads();
        off[tid] += add;
        __syncthreads();
    }
    int incl = off[tid];
    __syncthreads();
    off[tid] = incl - v;
    if (tid == 255) off[256] = incl;
    __syncthreads();

    // directory row + per-bin totals
    dir[t * DIRW + tid] = off[tid];
    if (tid == 0) dir[t * DIRW + 256] = off[256];
    if (v > 0) atomicAdd(&bin_cnt[tid], v);

    // phase C: place records into LDS at binned positions
    #pragma unroll
    for (int i = 0; i < EPT; ++i) {
        int b = myb[i];
        if (b >= 0) {
            int r = atomicAdd(&rnk[b], 1);
            buf[off[b] + r] = rec[i];
        }
    }
    __syncthreads();

    // phase D: sequential coalesced flush
    int total = off[256];
    for (int i = tid; i < total; i += K1_THREADS)
        records[(size_t)base + i] = buf[i];
}

// ---------------- K2: scan bin totals -> bin_base ----------------
__global__ __launch_bounds__(256)
void scan_bins_kernel(const int* __restrict__ bin_cnt,
                      int* __restrict__ bin_base,
                      int* __restrict__ row_ptr, int N, int NB) {
    __shared__ int tmp[256];
    int tid = threadIdx.x;
    int v = (tid < NB) ? bin_cnt[tid] : 0;
    tmp[tid] = v;
    __syncthreads();
    for (int d = 1; d < 256; d <<= 1) {
        int add = (tid >= d) ? tmp[tid - d] : 0;
        __syncthreads();
        tmp[tid] += add;
        __syncthreads();
    }
    bin_base[tid] = tmp[tid] - v;   // exclusive
    if (tid == 255) {
        bin_base[256] = tmp[255];
        row_ptr[N] = tmp[255];
    }
}

// ---------------- K3: per-bin CSR build ----------------
__global__ __launch_bounds__(256)
void csr_build_kernel(const u64* __restrict__ records,
                      const int* __restrict__ dir,
                      const int* __restrict__ bin_base,
                      float* __restrict__ dis,
                      int* __restrict__ row_ptr,
                      int* __restrict__ csr_src, int N, int NT) {
    __shared__ int deg[512];        // padded for scan
    __shared__ int cur[BIN_W];
    const int b  = blockIdx.x;
    const int lo = b * BIN_W;
    const int hi = min(lo + BIN_W, N);
    const int nodes = hi - lo;
    const int tid = threadIdx.x;
    const int wave = tid >> 6, lane = tid & 63;

    deg[tid] = 0;
    deg[tid + 256] = 0;
    __syncthreads();

    // pass 1: degree histogram over this bin's records
    for (int t = wave; t < NT; t += 4) {
        int s = dir[t * DIRW + b];
        int e = dir[t * DIRW + b + 1];
        int gb = t * TILE;
        for (int k = s + lane; k < e; k += 64) {
            int d = (int)(records[gb + k] >> 32);
            atomicAdd(&deg[d - lo], 1);
        }
    }
    __syncthreads();

    // dis slice (deg still intact)
    for (int i = tid; i < nodes; i += 256) {
        int c = deg[i];
        dis[lo + i] = (c > 0) ? rsqrtf((float)c) : 0.0f;
    }

    // save own values, then inclusive Hillis-Steele scan over 512 slots
    int v0 = deg[tid];
    int v1 = deg[tid + 256];
    __syncthreads();
    for (int d = 1; d < 512; d <<= 1) {
        int a0 = (tid >= d) ? deg[tid - d] : 0;
        int a1 = (tid + 256 >= d) ? deg[tid + 256 - d] : 0;
        __syncthreads();
        deg[tid] += a0;
        deg[tid + 256] += a1;
        __syncthreads();
    }

    // exclusive global positions -> row_ptr + cursors
    int gb0 = bin_base[b];
    if (tid < nodes) {
        int g = gb0 + deg[tid] - v0;
        row_ptr[lo + tid] = g;
        cur[tid] = g;
    }
    int i1 = tid + 256;
    if (i1 < nodes) {
        int g = gb0 + deg[i1] - v1;
        row_ptr[lo + i1] = g;
        cur[i1] = g;
    }
    __syncthreads();

    // pass 2: scatter src into the bin's private csr window (~25KB, L2-merged)
    for (int t = wave; t < NT; t += 4) {
        int s = dir[t * DIRW + b];
        int e = dir[t * DIRW + b + 1];
        int gb = t * TILE;
        for (int k = s + lane; k < e; k += 64) {
            u64 r = records[gb + k];
            int d = (int)(r >> 32);
            int sc = (int)(unsigned)r;
            int p = atomicAdd(&cur[d - lo], 1);
            csr_src[p] = sc;
        }
    }
}

// ---------------- K4: gather — one wave per dst node, lane = feature ----------------
__global__ void gather_kernel(const float* __restrict__ x,
                              const int* __restrict__ row_ptr,
                              const int* __restrict__ csr_src,
                              const float* __restrict__ dis,
                              float* __restrict__ out, int N) {
    int wid = (int)((blockIdx.x * (long long)blockDim.x + threadIdx.x) >> 6);
    int lane = threadIdx.x & 63;
    if (wid >= N) return;
    int beg = row_ptr[wid];
    int end = row_ptr[wid + 1];
    float dd = dis[wid];
    float acc = 0.0f;
    int k = beg;
    int n4 = beg + ((end - beg) & ~3);
    for (; k < n4; k += 4) {
        int s0 = __builtin_nontemporal_load(csr_src + k);
        int s1 = __builtin_nontemporal_load(csr_src + k + 1);
        int s2 = __builtin_nontemporal_load(csr_src + k + 2);
        int s3 = __builtin_nontemporal_load(csr_src + k + 3);
        float w0 = dis[s0], w1 = dis[s1], w2 = dis[s2], w3 = dis[s3];
        float v0 = x[(size_t)s0 * DFEAT + lane];
        float v1 = x[(size_t)s1 * DFEAT + lane];
        float v2 = x[(size_t)s2 * DFEAT + lane];
        float v3 = x[(size_t)s3 * DFEAT + lane];
        acc += v0 * (w0 * dd);
        acc += v1 * (w1 * dd);
        acc += v2 * (w2 * dd);
        acc += v3 * (w3 * dd);
    }
    for (; k < end; ++k) {
        int s0 = __builtin_nontemporal_load(csr_src + k);
        acc += x[(size_t)s0 * DFEAT + lane] * (dis[s0] * dd);
    }
    __builtin_nontemporal_store(acc, &out[(size_t)wid * DFEAT + lane]);
}

// ---------------- fallback (atomic scatter) if ws too small ----------------
__global__ void fb_deg_kernel(const int* __restrict__ dst,
                              float* __restrict__ deg, int E, int N) {
    int e = blockIdx.x * blockDim.x + threadIdx.x;
    if (e < E) {
        unsigned d = (unsigned)dst[e];
        if (d < (unsigned)N) unsafeAtomicAdd(&deg[d], 1.0f);
    }
}
__global__ void fb_dis_kernel(float* __restrict__ deg, int N) {
    int i = blockIdx.x * blockDim.x + threadIdx.x;
    if (i < N) {
        float d = deg[i];
        deg[i] = (d > 0.0f) ? rsqrtf(d) : 0.0f;
    }
}
__global__ void fb_scatter_kernel(const float* __restrict__ x,
                                  const int* __restrict__ src,
                                  const int* __restrict__ dst,
                                  const float* __restrict__ dis,
                                  float* __restrict__ out, int E, int N) {
    long long t = (long long)blockIdx.x * blockDim.x + threadIdx.x;
    int e = (int)(t >> 4);
    int c = (int)(t & 15);
    if (e >= E) return;
    unsigned s = (unsigned)src[e];
    unsigned d = (unsigned)dst[e];
    if (s >= (unsigned)N || d >= (unsigned)N) return;
    float norm = dis[s] * dis[d];
    const float4 v = *reinterpret_cast<const float4*>(x + (size_t)s * DFEAT + c * 4);
    float* o = out + (size_t)d * DFEAT + c * 4;
    unsafeAtomicAdd(o + 0, v.x * norm);
    unsafeAtomicAdd(o + 1, v.y * norm);
    unsafeAtomicAdd(o + 2, v.z * norm);
    unsafeAtomicAdd(o + 3, v.w * norm);
}

extern "C" void kernel_launch(void* const* d_in, const int* in_sizes, int n_in,
                              void* d_out, int out_size, void* d_ws, size_t ws_size,
                              hipStream_t stream) {
    const float* x  = (const float*)d_in[0];
    const int*   ei = (const int*)d_in[1];   // harness delivers integer inputs as int32

    const int N = in_sizes[0] / DFEAT;        // 100000
    const int E = in_sizes[1] / 2;            // 1600000
    const int* src = ei;                      // row 0
    const int* dst = ei + E;                  // row 1

    float* out = (float*)d_out;

    const int NB = (N + BIN_W - 1) / BIN_W;   // bins (256 for N=100000)
    const int NT = (E + TILE - 1) / TILE;     // tiles (391 for E=1.6M)

    // workspace layout (16B-aligned chunks)
    char* base = (char*)d_ws;
    size_t off = 0;
    auto alloc = [&](size_t bytes) { void* p = base + off; off += (bytes + 15) & ~(size_t)15; return p; };
    u64*   records  = (u64*)alloc((size_t)NT * TILE * 8);
    int*   dir      = (int*)alloc((size_t)NT * DIRW * 4);
    int*   bin_cnt  = (int*)alloc(256 * 4);
    int*   bin_base = (int*)alloc(257 * 4);
    float* dis      = (float*)alloc((size_t)N * 4);
    int*   row_ptr  = (int*)alloc((size_t)(N + 1) * 4);
    int*   csr_src  = (int*)alloc((size_t)E * 4);

    const bool ok = (off <= ws_size) && (NB <= 256);

    if (ok) {
        hipMemsetAsync(bin_cnt, 0, 256 * 4, stream);

        bin_kernel<<<NT, K1_THREADS, 0, stream>>>(src, dst, records, dir, bin_cnt, E, N);
        scan_bins_kernel<<<1, 256, 0, stream>>>(bin_cnt, bin_base, row_ptr, N, NB);
        csr_build_kernel<<<NB, 256, 0, stream>>>(records, dir, bin_base, dis, row_ptr, csr_src, N, NT);

        long long total = (long long)N * 64;
        int gb = (int)((total + 255) / 256);
        gather_kernel<<<gb, 256, 0, stream>>>(x, row_ptr, csr_src, dis, out, N);
    } else {
        // fallback: atomic scatter (needs only N floats of ws)
        float* deg = (float*)d_ws;
        hipMemsetAsync(deg, 0, (size_t)N * 4, stream);
        hipMemsetAsync(out, 0, (size_t)out_size * 4, stream);
        int eb = (E + 255) / 256;
        fb_deg_kernel<<<eb, 256, 0, stream>>>(dst, deg, E, N);
        int nb = (N + 255) / 256;
        fb_dis_kernel<<<nb, 256, 0, stream>>>(deg, N);
        long long total = (long long)E * 16;
        int sb = (int)((total + 255) / 256);
        fb_scatter_kernel<<<sb, 256, 0, stream>>>(x, src, dst, deg, out, E, N);
    }
}

// Round 8
// 140.517 us; speedup vs baseline: 4.7565x; 1.5994x over previous
//
#include <hip/hip_runtime.h>

// LGConv: out = D^{-1/2} A D^{-1/2} x
// x: f32 [N, 64]; edge_index: int32 on device (harness downcasts int64), [2, E]
//
// Pipeline:
//  K1 bin_kernel: per 4096-edge tile, LDS count/scan/reorder by dst-bin (256
//     bins of BIN_W nodes), sequential flush of {dst,src} records + per-tile
//     directory + per-bin totals. No random global writes.
//  K2 scan_bins: exclusive scan of bin totals -> bin_base, row_ptr[N].
//  K3 csr_build: one 1024-thread block per bin (16 waves; dir run-bounds
//     cached in LDS so record loads pipeline): histogram -> dis + row_ptr,
//     then scatter csr_src into the bin's private ~25KB window (L2-merged).
//  K4 gather: one wave per dst node, lane = feature dim; exact CSR; unroll 4.

#define DFEAT 64
#define BIN_W 391          // nodes per bin; NB = ceil(N/BIN_W) must be <= 256
#define TILE 4096          // edges per K1 block
#define K1_THREADS 256
#define EPT (TILE / K1_THREADS)   // 16
#define DIRW 257
#define K3_THREADS 1024
#define K3_WAVES (K3_THREADS / 64)   // 16
#define MAX_NT 512         // LDS run-bound cache capacity; NT must be <= this

typedef unsigned long long u64;

// ---------------- K1: LDS-reordered binning ----------------
__global__ __launch_bounds__(K1_THREADS)
void bin_kernel(const int* __restrict__ src, const int* __restrict__ dst,
                u64* __restrict__ records, int* __restrict__ dir,
                int* __restrict__ bin_cnt, int E, int N) {
    __shared__ int cnt[256];
    __shared__ int off[DIRW];
    __shared__ int rnk[256];
    __shared__ u64 buf[TILE];

    const int t    = blockIdx.x;
    const int base = t * TILE;
    const int tid  = threadIdx.x;

    cnt[tid] = 0;
    rnk[tid] = 0;
    __syncthreads();

    // phase A: load + count (validates indices; keep records in regs)
    u64 rec[EPT];
    int myb[EPT];
    #pragma unroll
    for (int i = 0; i < EPT; ++i) {
        int e = base + tid + i * K1_THREADS;
        int b = -1;
        u64 r = 0;
        if (e < E) {
            unsigned d = (unsigned)dst[e];
            unsigned s = (unsigned)src[e];
            if (d < (unsigned)N && s < (unsigned)N) {
                b = (int)(d / BIN_W);
                r = ((u64)d << 32) | (u64)s;
            }
        }
        myb[i] = b;
        rec[i] = r;
        if (b >= 0) atomicAdd(&cnt[b], 1);
    }
    __syncthreads();

    // phase B: exclusive scan of cnt -> off
    int v = cnt[tid];
    off[tid] = v;
    __syncthreads();
    for (int d = 1; d < 256; d <<= 1) {
        int add = (tid >= d) ? off[tid - d] : 0;
        __syncthreads();
        off[tid] += add;
        __syncthreads();
    }
    int incl = off[tid];
    __syncthreads();
    off[tid] = incl - v;
    if (tid == 255) off[256] = incl;
    __syncthreads();

    // directory row + per-bin totals
    dir[t * DIRW + tid] = off[tid];
    if (tid == 0) dir[t * DIRW + 256] = off[256];
    if (v > 0) atomicAdd(&bin_cnt[tid], v);

    // phase C: place records into LDS at binned positions
    #pragma unroll
    for (int i = 0; i < EPT; ++i) {
        int b = myb[i];
        if (b >= 0) {
            int r = atomicAdd(&rnk[b], 1);
            buf[off[b] + r] = rec[i];
        }
    }
    __syncthreads();

    // phase D: sequential coalesced flush
    int total = off[256];
    for (int i = tid; i < total; i += K1_THREADS)
        records[(size_t)base + i] = buf[i];
}

// ---------------- K2: scan bin totals -> bin_base ----------------
__global__ __launch_bounds__(256)
void scan_bins_kernel(const int* __restrict__ bin_cnt,
                      int* __restrict__ bin_base,
                      int* __restrict__ row_ptr, int N, int NB) {
    __shared__ int tmp[256];
    int tid = threadIdx.x;
    int v = (tid < NB) ? bin_cnt[tid] : 0;
    tmp[tid] = v;
    __syncthreads();
    for (int d = 1; d < 256; d <<= 1) {
        int add = (tid >= d) ? tmp[tid - d] : 0;
        __syncthreads();
        tmp[tid] += add;
        __syncthreads();
    }
    bin_base[tid] = tmp[tid] - v;   // exclusive
    if (tid == 255) {
        bin_base[256] = tmp[255];
        row_ptr[N] = tmp[255];
    }
}

// ---------------- K3: per-bin CSR build (16 waves, LDS-cached bounds) ----------------
__global__ __launch_bounds__(K3_THREADS)
void csr_build_kernel(const u64* __restrict__ records,
                      const int* __restrict__ dir,
                      const int* __restrict__ bin_base,
                      float* __restrict__ dis,
                      int* __restrict__ row_ptr,
                      int* __restrict__ csr_src, int N, int NT) {
    __shared__ int deg[512];        // padded to pow2 for scan
    __shared__ int cur[BIN_W];
    __shared__ int sbeg[MAX_NT];
    __shared__ int send[MAX_NT];

    const int b  = blockIdx.x;
    const int lo = b * BIN_W;
    const int hi = min(lo + BIN_W, N);
    const int nodes = hi - lo;
    const int tid = threadIdx.x;
    const int wave = tid >> 6, lane = tid & 63;

    if (tid < 512) deg[tid] = 0;
    // cache this bin's run bounds: one parallel burst, kills the dependent
    // dir->records load chain in both record passes
    for (int t = tid; t < NT; t += K3_THREADS) {
        sbeg[t] = dir[t * DIRW + b];
        send[t] = dir[t * DIRW + b + 1];
    }
    __syncthreads();

    // pass 1: degree histogram over this bin's records
    for (int t = wave; t < NT; t += K3_WAVES) {
        int s = sbeg[t], e = send[t];
        int gb = t * TILE;
        for (int k = s + lane; k < e; k += 64) {
            int d = (int)(records[gb + k] >> 32);
            atomicAdd(&deg[d - lo], 1);
        }
    }
    __syncthreads();

    // dis slice (deg still intact; nodes <= BIN_W < 1024)
    if (tid < nodes) {
        int c = deg[tid];
        dis[lo + tid] = (c > 0) ? rsqrtf((float)c) : 0.0f;
    }

    // inclusive Hillis-Steele scan over 512 slots (threads >=512 only barrier)
    int v0 = (tid < 512) ? deg[tid] : 0;
    __syncthreads();
    for (int d = 1; d < 512; d <<= 1) {
        int a = 0;
        if (tid < 512 && tid >= d) a = deg[tid - d];
        __syncthreads();
        if (tid < 512) deg[tid] += a;
        __syncthreads();
    }

    // exclusive global positions -> row_ptr + cursors
    int gb0 = bin_base[b];
    if (tid < nodes) {
        int g = gb0 + deg[tid] - v0;
        row_ptr[lo + tid] = g;
        cur[tid] = g;
    }
    __syncthreads();

    // pass 2: scatter src into the bin's private csr window (~25KB, L2-merged)
    for (int t = wave; t < NT; t += K3_WAVES) {
        int s = sbeg[t], e = send[t];
        int gb = t * TILE;
        for (int k = s + lane; k < e; k += 64) {
            u64 r = records[gb + k];
            int d = (int)(r >> 32);
            int p = atomicAdd(&cur[d - lo], 1);
            csr_src[p] = (int)(unsigned)r;
        }
    }
}

// ---------------- K4: gather — one wave per dst node, lane = feature ----------------
__global__ void gather_kernel(const float* __restrict__ x,
                              const int* __restrict__ row_ptr,
                              const int* __restrict__ csr_src,
                              const float* __restrict__ dis,
                              float* __restrict__ out, int N) {
    int wid = (int)((blockIdx.x * (long long)blockDim.x + threadIdx.x) >> 6);
    int lane = threadIdx.x & 63;
    if (wid >= N) return;
    int beg = row_ptr[wid];
    int end = row_ptr[wid + 1];
    float dd = dis[wid];
    float acc = 0.0f;
    int k = beg;
    int n4 = beg + ((end - beg) & ~3);
    for (; k < n4; k += 4) {
        int s0 = __builtin_nontemporal_load(csr_src + k);
        int s1 = __builtin_nontemporal_load(csr_src + k + 1);
        int s2 = __builtin_nontemporal_load(csr_src + k + 2);
        int s3 = __builtin_nontemporal_load(csr_src + k + 3);
        float w0 = dis[s0], w1 = dis[s1], w2 = dis[s2], w3 = dis[s3];
        float v0 = x[(size_t)s0 * DFEAT + lane];
        float v1 = x[(size_t)s1 * DFEAT + lane];
        float v2 = x[(size_t)s2 * DFEAT + lane];
        float v3 = x[(size_t)s3 * DFEAT + lane];
        acc += v0 * (w0 * dd);
        acc += v1 * (w1 * dd);
        acc += v2 * (w2 * dd);
        acc += v3 * (w3 * dd);
    }
    for (; k < end; ++k) {
        int s0 = __builtin_nontemporal_load(csr_src + k);
        acc += x[(size_t)s0 * DFEAT + lane] * (dis[s0] * dd);
    }
    __builtin_nontemporal_store(acc, &out[(size_t)wid * DFEAT + lane]);
}

// ---------------- fallback (atomic scatter) if ws too small ----------------
__global__ void fb_deg_kernel(const int* __restrict__ dst,
                              float* __restrict__ deg, int E, int N) {
    int e = blockIdx.x * blockDim.x + threadIdx.x;
    if (e < E) {
        unsigned d = (unsigned)dst[e];
        if (d < (unsigned)N) unsafeAtomicAdd(&deg[d], 1.0f);
    }
}
__global__ void fb_dis_kernel(float* __restrict__ deg, int N) {
    int i = blockIdx.x * blockDim.x + threadIdx.x;
    if (i < N) {
        float d = deg[i];
        deg[i] = (d > 0.0f) ? rsqrtf(d) : 0.0f;
    }
}
__global__ void fb_scatter_kernel(const float* __restrict__ x,
                                  const int* __restrict__ src,
                                  const int* __restrict__ dst,
                                  const float* __restrict__ dis,
                                  float* __restrict__ out, int E, int N) {
    long long t = (long long)blockIdx.x * blockDim.x + threadIdx.x;
    int e = (int)(t >> 4);
    int c = (int)(t & 15);
    if (e >= E) return;
    unsigned s = (unsigned)src[e];
    unsigned d = (unsigned)dst[e];
    if (s >= (unsigned)N || d >= (unsigned)N) return;
    float norm = dis[s] * dis[d];
    const float4 v = *reinterpret_cast<const float4*>(x + (size_t)s * DFEAT + c * 4);
    float* o = out + (size_t)d * DFEAT + c * 4;
    unsafeAtomicAdd(o + 0, v.x * norm);
    unsafeAtomicAdd(o + 1, v.y * norm);
    unsafeAtomicAdd(o + 2, v.z * norm);
    unsafeAtomicAdd(o + 3, v.w * norm);
}

extern "C" void kernel_launch(void* const* d_in, const int* in_sizes, int n_in,
                              void* d_out, int out_size, void* d_ws, size_t ws_size,
                              hipStream_t stream) {
    const float* x  = (const float*)d_in[0];
    const int*   ei = (const int*)d_in[1];   // harness delivers integer inputs as int32

    const int N = in_sizes[0] / DFEAT;        // 100000
    const int E = in_sizes[1] / 2;            // 1600000
    const int* src = ei;                      // row 0
    const int* dst = ei + E;                  // row 1

    float* out = (float*)d_out;

    const int NB = (N + BIN_W - 1) / BIN_W;   // bins (256 for N=100000)
    const int NT = (E + TILE - 1) / TILE;     // tiles (391 for E=1.6M)

    // workspace layout (16B-aligned chunks)
    char* base = (char*)d_ws;
    size_t off = 0;
    auto alloc = [&](size_t bytes) { void* p = base + off; off += (bytes + 15) & ~(size_t)15; return p; };
    u64*   records  = (u64*)alloc((size_t)NT * TILE * 8);
    int*   dir      = (int*)alloc((size_t)NT * DIRW * 4);
    int*   bin_cnt  = (int*)alloc(256 * 4);
    int*   bin_base = (int*)alloc(257 * 4);
    float* dis      = (float*)alloc((size_t)N * 4);
    int*   row_ptr  = (int*)alloc((size_t)(N + 1) * 4);
    int*   csr_src  = (int*)alloc((size_t)E * 4);

    const bool ok = (off <= ws_size) && (NB <= 256) && (NT <= MAX_NT);

    if (ok) {
        hipMemsetAsync(bin_cnt, 0, 256 * 4, stream);

        bin_kernel<<<NT, K1_THREADS, 0, stream>>>(src, dst, records, dir, bin_cnt, E, N);
        scan_bins_kernel<<<1, 256, 0, stream>>>(bin_cnt, bin_base, row_ptr, N, NB);
        csr_build_kernel<<<NB, K3_THREADS, 0, stream>>>(records, dir, bin_base, dis, row_ptr, csr_src, N, NT);

        long long total = (long long)N * 64;
        int gb = (int)((total + 255) / 256);
        gather_kernel<<<gb, 256, 0, stream>>>(x, row_ptr, csr_src, dis, out, N);
    } else {
        // fallback: atomic scatter (needs only N floats of ws)
        float* deg = (float*)d_ws;
        hipMemsetAsync(deg, 0, (size_t)N * 4, stream);
        hipMemsetAsync(out, 0, (size_t)out_size * 4, stream);
        int eb = (E + 255) / 256;
        fb_deg_kernel<<<eb, 256, 0, stream>>>(dst, deg, E, N);
        int nb = (N + 255) / 256;
        fb_dis_kernel<<<nb, 256, 0, stream>>>(deg, N);
        long long total = (long long)E * 16;
        int sb = (int)((total + 255) / 256);
        fb_scatter_kernel<<<sb, 256, 0, stream>>>(x, src, dst, deg, out, E, N);
    }
}

// Round 9
// 140.396 us; speedup vs baseline: 4.7607x; 1.0009x over previous
//
#include <hip/hip_runtime.h>

// LGConv: out = D^{-1/2} A D^{-1/2} x
// x: f32 [N, 64]; edge_index: int32 on device (harness downcasts int64), [2, E]
//
// Pipeline:
//  K1 bin_kernel: per 4096-edge tile, LDS count/scan/reorder by dst-bin (256
//     bins of BIN_W nodes), sequential flush of {dst,src} records + per-tile
//     directory + per-bin totals. No random global writes.
//  K2 scan_bins: exclusive scan of bin totals -> bin_base, row_ptr[N].
//  K3 csr_build: one 1024-thread block per bin (16 waves; dir run-bounds
//     cached in LDS so record loads pipeline): histogram -> dis + row_ptr,
//     then scatter csr_src into the bin's private ~25KB window (L2-merged).
//  K4 gather: one wave per dst node, lane = feature dim; exact CSR; unroll 4.

#define DFEAT 64
#define BIN_W 391          // nodes per bin; NB = ceil(N/BIN_W) must be <= 256
#define TILE 4096          // edges per K1 block
#define K1_THREADS 256
#define EPT (TILE / K1_THREADS)   // 16
#define DIRW 257
#define K3_THREADS 1024
#define K3_WAVES (K3_THREADS / 64)   // 16
#define MAX_NT 512         // LDS run-bound cache capacity; NT must be <= this

typedef unsigned long long u64;

// ---------------- K1: LDS-reordered binning ----------------
__global__ __launch_bounds__(K1_THREADS)
void bin_kernel(const int* __restrict__ src, const int* __restrict__ dst,
                u64* __restrict__ records, int* __restrict__ dir,
                int* __restrict__ bin_cnt, int E, int N) {
    __shared__ int cnt[256];
    __shared__ int off[DIRW];
    __shared__ int rnk[256];
    __shared__ u64 buf[TILE];

    const int t    = blockIdx.x;
    const int base = t * TILE;
    const int tid  = threadIdx.x;

    cnt[tid] = 0;
    rnk[tid] = 0;
    __syncthreads();

    // phase A: load + count (validates indices; keep records in regs)
    u64 rec[EPT];
    int myb[EPT];
    #pragma unroll
    for (int i = 0; i < EPT; ++i) {
        int e = base + tid + i * K1_THREADS;
        int b = -1;
        u64 r = 0;
        if (e < E) {
            unsigned d = (unsigned)dst[e];
            unsigned s = (unsigned)src[e];
            if (d < (unsigned)N && s < (unsigned)N) {
                b = (int)(d / BIN_W);
                r = ((u64)d << 32) | (u64)s;
            }
        }
        myb[i] = b;
        rec[i] = r;
        if (b >= 0) atomicAdd(&cnt[b], 1);
    }
    __syncthreads();

    // phase B: exclusive scan of cnt -> off
    int v = cnt[tid];
    off[tid] = v;
    __syncthreads();
    for (int d = 1; d < 256; d <<= 1) {
        int add = (tid >= d) ? off[tid - d] : 0;
        __syncthreads();
        off[tid] += add;
        __syncthreads();
    }
    int incl = off[tid];
    __syncthreads();
    off[tid] = incl - v;
    if (tid == 255) off[256] = incl;
    __syncthreads();

    // directory row + per-bin totals
    dir[t * DIRW + tid] = off[tid];
    if (tid == 0) dir[t * DIRW + 256] = off[256];
    if (v > 0) atomicAdd(&bin_cnt[tid], v);

    // phase C: place records into LDS at binned positions
    #pragma unroll
    for (int i = 0; i < EPT; ++i) {
        int b = myb[i];
        if (b >= 0) {
            int r = atomicAdd(&rnk[b], 1);
            buf[off[b] + r] = rec[i];
        }
    }
    __syncthreads();

    // phase D: sequential coalesced flush
    int total = off[256];
    for (int i = tid; i < total; i += K1_THREADS)
        records[(size_t)base + i] = buf[i];
}

// ---------------- K2: scan bin totals -> bin_base ----------------
__global__ __launch_bounds__(256)
void scan_bins_kernel(const int* __restrict__ bin_cnt,
                      int* __restrict__ bin_base,
                      int* __restrict__ row_ptr, int N, int NB) {
    __shared__ int tmp[256];
    int tid = threadIdx.x;
    int v = (tid < NB) ? bin_cnt[tid] : 0;
    tmp[tid] = v;
    __syncthreads();
    for (int d = 1; d < 256; d <<= 1) {
        int add = (tid >= d) ? tmp[tid - d] : 0;
        __syncthreads();
        tmp[tid] += add;
        __syncthreads();
    }
    bin_base[tid] = tmp[tid] - v;   // exclusive
    if (tid == 255) {
        bin_base[256] = tmp[255];
        row_ptr[N] = tmp[255];
    }
}

// ---------------- K3: per-bin CSR build (16 waves, LDS-cached bounds) ----------------
__global__ __launch_bounds__(K3_THREADS)
void csr_build_kernel(const u64* __restrict__ records,
                      const int* __restrict__ dir,
                      const int* __restrict__ bin_base,
                      float* __restrict__ dis,
                      int* __restrict__ row_ptr,
                      int* __restrict__ csr_src, int N, int NT) {
    __shared__ int deg[512];        // padded to pow2 for scan
    __shared__ int cur[BIN_W];
    __shared__ int sbeg[MAX_NT];
    __shared__ int send[MAX_NT];

    const int b  = blockIdx.x;
    const int lo = b * BIN_W;
    const int hi = min(lo + BIN_W, N);
    const int nodes = hi - lo;
    const int tid = threadIdx.x;
    const int wave = tid >> 6, lane = tid & 63;

    if (tid < 512) deg[tid] = 0;
    // cache this bin's run bounds: one parallel burst, kills the dependent
    // dir->records load chain in both record passes
    for (int t = tid; t < NT; t += K3_THREADS) {
        sbeg[t] = dir[t * DIRW + b];
        send[t] = dir[t * DIRW + b + 1];
    }
    __syncthreads();

    // pass 1: degree histogram over this bin's records
    for (int t = wave; t < NT; t += K3_WAVES) {
        int s = sbeg[t], e = send[t];
        int gb = t * TILE;
        for (int k = s + lane; k < e; k += 64) {
            int d = (int)(records[gb + k] >> 32);
            atomicAdd(&deg[d - lo], 1);
        }
    }
    __syncthreads();

    // dis slice (deg still intact; nodes <= BIN_W < 1024)
    if (tid < nodes) {
        int c = deg[tid];
        dis[lo + tid] = (c > 0) ? rsqrtf((float)c) : 0.0f;
    }

    // inclusive Hillis-Steele scan over 512 slots (threads >=512 only barrier)
    int v0 = (tid < 512) ? deg[tid] : 0;
    __syncthreads();
    for (int d = 1; d < 512; d <<= 1) {
        int a = 0;
        if (tid < 512 && tid >= d) a = deg[tid - d];
        __syncthreads();
        if (tid < 512) deg[tid] += a;
        __syncthreads();
    }

    // exclusive global positions -> row_ptr + cursors
    int gb0 = bin_base[b];
    if (tid < nodes) {
        int g = gb0 + deg[tid] - v0;
        row_ptr[lo + tid] = g;
        cur[tid] = g;
    }
    __syncthreads();

    // pass 2: scatter src into the bin's private csr window (~25KB, L2-merged)
    for (int t = wave; t < NT; t += K3_WAVES) {
        int s = sbeg[t], e = send[t];
        int gb = t * TILE;
        for (int k = s + lane; k < e; k += 64) {
            u64 r = records[gb + k];
            int d = (int)(r >> 32);
            int p = atomicAdd(&cur[d - lo], 1);
            csr_src[p] = (int)(unsigned)r;
        }
    }
}

// ---------------- K4: gather — one wave per dst node, lane = feature ----------------
__global__ void gather_kernel(const float* __restrict__ x,
                              const int* __restrict__ row_ptr,
                              const int* __restrict__ csr_src,
                              const float* __restrict__ dis,
                              float* __restrict__ out, int N) {
    int wid = (int)((blockIdx.x * (long long)blockDim.x + threadIdx.x) >> 6);
    int lane = threadIdx.x & 63;
    if (wid >= N) return;
    int beg = row_ptr[wid];
    int end = row_ptr[wid + 1];
    float dd = dis[wid];
    float acc = 0.0f;
    int k = beg;
    int n4 = beg + ((end - beg) & ~3);
    for (; k < n4; k += 4) {
        int s0 = __builtin_nontemporal_load(csr_src + k);
        int s1 = __builtin_nontemporal_load(csr_src + k + 1);
        int s2 = __builtin_nontemporal_load(csr_src + k + 2);
        int s3 = __builtin_nontemporal_load(csr_src + k + 3);
        float w0 = dis[s0], w1 = dis[s1], w2 = dis[s2], w3 = dis[s3];
        float v0 = x[(size_t)s0 * DFEAT + lane];
        float v1 = x[(size_t)s1 * DFEAT + lane];
        float v2 = x[(size_t)s2 * DFEAT + lane];
        float v3 = x[(size_t)s3 * DFEAT + lane];
        acc += v0 * (w0 * dd);
        acc += v1 * (w1 * dd);
        acc += v2 * (w2 * dd);
        acc += v3 * (w3 * dd);
    }
    for (; k < end; ++k) {
        int s0 = __builtin_nontemporal_load(csr_src + k);
        acc += x[(size_t)s0 * DFEAT + lane] * (dis[s0] * dd);
    }
    __builtin_nontemporal_store(acc, &out[(size_t)wid * DFEAT + lane]);
}

// ---------------- fallback (atomic scatter) if ws too small ----------------
__global__ void fb_deg_kernel(const int* __restrict__ dst,
                              float* __restrict__ deg, int E, int N) {
    int e = blockIdx.x * blockDim.x + threadIdx.x;
    if (e < E) {
        unsigned d = (unsigned)dst[e];
        if (d < (unsigned)N) unsafeAtomicAdd(&deg[d], 1.0f);
    }
}
__global__ void fb_dis_kernel(float* __restrict__ deg, int N) {
    int i = blockIdx.x * blockDim.x + threadIdx.x;
    if (i < N) {
        float d = deg[i];
        deg[i] = (d > 0.0f) ? rsqrtf(d) : 0.0f;
    }
}
__global__ void fb_scatter_kernel(const float* __restrict__ x,
                                  const int* __restrict__ src,
                                  const int* __restrict__ dst,
                                  const float* __restrict__ dis,
                                  float* __restrict__ out, int E, int N) {
    long long t = (long long)blockIdx.x * blockDim.x + threadIdx.x;
    int e = (int)(t >> 4);
    int c = (int)(t & 15);
    if (e >= E) return;
    unsigned s = (unsigned)src[e];
    unsigned d = (unsigned)dst[e];
    if (s >= (unsigned)N || d >= (unsigned)N) return;
    float norm = dis[s] * dis[d];
    const float4 v = *reinterpret_cast<const float4*>(x + (size_t)s * DFEAT + c * 4);
    float* o = out + (size_t)d * DFEAT + c * 4;
    unsafeAtomicAdd(o + 0, v.x * norm);
    unsafeAtomicAdd(o + 1, v.y * norm);
    unsafeAtomicAdd(o + 2, v.z * norm);
    unsafeAtomicAdd(o + 3, v.w * norm);
}

extern "C" void kernel_launch(void* const* d_in, const int* in_sizes, int n_in,
                              void* d_out, int out_size, void* d_ws, size_t ws_size,
                              hipStream_t stream) {
    const float* x  = (const float*)d_in[0];
    const int*   ei = (const int*)d_in[1];   // harness delivers integer inputs as int32

    const int N = in_sizes[0] / DFEAT;        // 100000
    const int E = in_sizes[1] / 2;            // 1600000
    const int* src = ei;                      // row 0
    const int* dst = ei + E;                  // row 1

    float* out = (float*)d_out;

    const int NB = (N + BIN_W - 1) / BIN_W;   // bins (256 for N=100000)
    const int NT = (E + TILE - 1) / TILE;     // tiles (391 for E=1.6M)

    // workspace layout (16B-aligned chunks)
    char* base = (char*)d_ws;
    size_t off = 0;
    auto alloc = [&](size_t bytes) { void* p = base + off; off += (bytes + 15) & ~(size_t)15; return p; };
    u64*   records  = (u64*)alloc((size_t)NT * TILE * 8);
    int*   dir      = (int*)alloc((size_t)NT * DIRW * 4);
    int*   bin_cnt  = (int*)alloc(256 * 4);
    int*   bin_base = (int*)alloc(257 * 4);
    float* dis      = (float*)alloc((size_t)N * 4);
    int*   row_ptr  = (int*)alloc((size_t)(N + 1) * 4);
    int*   csr_src  = (int*)alloc((size_t)E * 4);

    const bool ok = (off <= ws_size) && (NB <= 256) && (NT <= MAX_NT);

    if (ok) {
        hipMemsetAsync(bin_cnt, 0, 256 * 4, stream);

        bin_kernel<<<NT, K1_THREADS, 0, stream>>>(src, dst, records, dir, bin_cnt, E, N);
        scan_bins_kernel<<<1, 256, 0, stream>>>(bin_cnt, bin_base, row_ptr, N, NB);
        csr_build_kernel<<<NB, K3_THREADS, 0, stream>>>(records, dir, bin_base, dis, row_ptr, csr_src, N, NT);

        long long total = (long long)N * 64;
        int gb = (int)((total + 255) / 256);
        gather_kernel<<<gb, 256, 0, stream>>>(x, row_ptr, csr_src, dis, out, N);
    } else {
        // fallback: atomic scatter (needs only N floats of ws)
        float* deg = (float*)d_ws;
        hipMemsetAsync(deg, 0, (size_t)N * 4, stream);
        hipMemsetAsync(out, 0, (size_t)out_size * 4, stream);
        int eb = (E + 255) / 256;
        fb_deg_kernel<<<eb, 256, 0, stream>>>(dst, deg, E, N);
        int nb = (N + 255) / 256;
        fb_dis_kernel<<<nb, 256, 0, stream>>>(deg, N);
        long long total = (long long)E * 16;
        int sb = (int)((total + 255) / 256);
        fb_scatter_kernel<<<sb, 256, 0, stream>>>(x, src, dst, deg, out, E, N);
    }
}

// Round 11
// 125.180 us; speedup vs baseline: 5.3393x; 1.1215x over previous
//
#include <hip/hip_runtime.h>
#include <hip/hip_fp16.h>

// LGConv: out = D^{-1/2} A D^{-1/2} x
// x: f32 [N, 64]; edge_index: int32 on device (harness downcasts int64), [2, E]
//
// Pipeline:
//  K1 bin_kernel: per 4096-edge tile, LDS count/scan/reorder by dst-bin (256
//     bins of BIN_W nodes), sequential flush of {dst,src} records + per-tile
//     directory + per-bin totals. No random global writes.
//  K2 scan_bins: exclusive scan of bin totals -> bin_base, row_ptr[N].
//  K3 csr_build: one 1024-thread block per bin (16 waves; dir run-bounds
//     cached in LDS): histogram -> dis + row_ptr, then scatter csr_src into
//     the bin's private ~25KB window (L2-merged writeback).
//  K4 stage_xh: x f32 -> fp16 (__half2), overlaid on dead records buffer.
//  K5 gather_h: one wave per dst node; lane = (edge-of-pair, half2-col):
//     2 edges/iter, 128B per edge-row (2 lines, was 4), unroll x4,
//     cross-half shfl reduce, scalar nontemporal out stores.

#define DFEAT 64
#define BIN_W 391          // nodes per bin; NB = ceil(N/BIN_W) must be <= 256
#define TILE 4096          // edges per K1 block
#define K1_THREADS 256
#define EPT (TILE / K1_THREADS)   // 16
#define DIRW 257
#define K3_THREADS 1024
#define K3_WAVES (K3_THREADS / 64)   // 16
#define MAX_NT 512         // LDS run-bound cache capacity; NT must be <= this

typedef unsigned long long u64;

// ---------------- K1: LDS-reordered binning ----------------
__global__ __launch_bounds__(K1_THREADS)
void bin_kernel(const int* __restrict__ src, const int* __restrict__ dst,
                u64* __restrict__ records, int* __restrict__ dir,
                int* __restrict__ bin_cnt, int E, int N) {
    __shared__ int cnt[256];
    __shared__ int off[DIRW];
    __shared__ int rnk[256];
    __shared__ u64 buf[TILE];

    const int t    = blockIdx.x;
    const int base = t * TILE;
    const int tid  = threadIdx.x;

    cnt[tid] = 0;
    rnk[tid] = 0;
    __syncthreads();

    // phase A: load + count (validates indices; keep records in regs)
    u64 rec[EPT];
    int myb[EPT];
    #pragma unroll
    for (int i = 0; i < EPT; ++i) {
        int e = base + tid + i * K1_THREADS;
        int b = -1;
        u64 r = 0;
        if (e < E) {
            unsigned d = (unsigned)dst[e];
            unsigned s = (unsigned)src[e];
            if (d < (unsigned)N && s < (unsigned)N) {
                b = (int)(d / BIN_W);
                r = ((u64)d << 32) | (u64)s;
            }
        }
        myb[i] = b;
        rec[i] = r;
        if (b >= 0) atomicAdd(&cnt[b], 1);
    }
    __syncthreads();

    // phase B: exclusive scan of cnt -> off
    int v = cnt[tid];
    off[tid] = v;
    __syncthreads();
    for (int d = 1; d < 256; d <<= 1) {
        int add = (tid >= d) ? off[tid - d] : 0;
        __syncthreads();
        off[tid] += add;
        __syncthreads();
    }
    int incl = off[tid];
    __syncthreads();
    off[tid] = incl - v;
    if (tid == 255) off[256] = incl;
    __syncthreads();

    // directory row + per-bin totals
    dir[t * DIRW + tid] = off[tid];
    if (tid == 0) dir[t * DIRW + 256] = off[256];
    if (v > 0) atomicAdd(&bin_cnt[tid], v);

    // phase C: place records into LDS at binned positions
    #pragma unroll
    for (int i = 0; i < EPT; ++i) {
        int b = myb[i];
        if (b >= 0) {
            int r = atomicAdd(&rnk[b], 1);
            buf[off[b] + r] = rec[i];
        }
    }
    __syncthreads();

    // phase D: sequential coalesced flush
    int total = off[256];
    for (int i = tid; i < total; i += K1_THREADS)
        records[(size_t)base + i] = buf[i];
}

// ---------------- K2: scan bin totals -> bin_base ----------------
__global__ __launch_bounds__(256)
void scan_bins_kernel(const int* __restrict__ bin_cnt,
                      int* __restrict__ bin_base,
                      int* __restrict__ row_ptr, int N, int NB) {
    __shared__ int tmp[256];
    int tid = threadIdx.x;
    int v = (tid < NB) ? bin_cnt[tid] : 0;
    tmp[tid] = v;
    __syncthreads();
    for (int d = 1; d < 256; d <<= 1) {
        int add = (tid >= d) ? tmp[tid - d] : 0;
        __syncthreads();
        tmp[tid] += add;
        __syncthreads();
    }
    bin_base[tid] = tmp[tid] - v;   // exclusive
    if (tid == 255) {
        bin_base[256] = tmp[255];
        row_ptr[N] = tmp[255];
    }
}

// ---------------- K3: per-bin CSR build (16 waves, LDS-cached bounds) ----------------
__global__ __launch_bounds__(K3_THREADS)
void csr_build_kernel(const u64* __restrict__ records,
                      const int* __restrict__ dir,
                      const int* __restrict__ bin_base,
                      float* __restrict__ dis,
                      int* __restrict__ row_ptr,
                      int* __restrict__ csr_src, int N, int NT) {
    __shared__ int deg[512];        // padded to pow2 for scan
    __shared__ int cur[BIN_W];
    __shared__ int sbeg[MAX_NT];
    __shared__ int send[MAX_NT];

    const int b  = blockIdx.x;
    const int lo = b * BIN_W;
    const int hi = min(lo + BIN_W, N);
    const int nodes = hi - lo;
    const int tid = threadIdx.x;
    const int wave = tid >> 6, lane = tid & 63;

    if (tid < 512) deg[tid] = 0;
    // cache this bin's run bounds: kills the dependent dir->records chain
    for (int t = tid; t < NT; t += K3_THREADS) {
        sbeg[t] = dir[t * DIRW + b];
        send[t] = dir[t * DIRW + b + 1];
    }
    __syncthreads();

    // pass 1: degree histogram over this bin's records
    for (int t = wave; t < NT; t += K3_WAVES) {
        int s = sbeg[t], e = send[t];
        int gb = t * TILE;
        for (int k = s + lane; k < e; k += 64) {
            int d = (int)(records[gb + k] >> 32);
            atomicAdd(&deg[d - lo], 1);
        }
    }
    __syncthreads();

    // dis slice (deg still intact; nodes <= BIN_W < 1024)
    if (tid < nodes) {
        int c = deg[tid];
        dis[lo + tid] = (c > 0) ? rsqrtf((float)c) : 0.0f;
    }

    // inclusive Hillis-Steele scan over 512 slots
    int v0 = (tid < 512) ? deg[tid] : 0;
    __syncthreads();
    for (int d = 1; d < 512; d <<= 1) {
        int a = 0;
        if (tid < 512 && tid >= d) a = deg[tid - d];
        __syncthreads();
        if (tid < 512) deg[tid] += a;
        __syncthreads();
    }

    // exclusive global positions -> row_ptr + cursors
    int gb0 = bin_base[b];
    if (tid < nodes) {
        int g = gb0 + deg[tid] - v0;
        row_ptr[lo + tid] = g;
        cur[tid] = g;
    }
    __syncthreads();

    // pass 2: scatter src into the bin's private csr window (~25KB, L2-merged)
    for (int t = wave; t < NT; t += K3_WAVES) {
        int s = sbeg[t], e = send[t];
        int gb = t * TILE;
        for (int k = s + lane; k < e; k += 64) {
            u64 r = records[gb + k];
            int d = (int)(r >> 32);
            int p = atomicAdd(&cur[d - lo], 1);
            csr_src[p] = (int)(unsigned)r;
        }
    }
}

// ---------------- K4: stage x -> fp16 (__half2 pairs) ----------------
// each thread: 2 half2 = 4 floats
__global__ __launch_bounds__(256)
void stage_xh_kernel(const float* __restrict__ x, __half2* __restrict__ xh,
                     int total4 /* N*DFEAT/4 */) {
    int i = blockIdx.x * blockDim.x + threadIdx.x;
    if (i < total4) {
        float4 f = *reinterpret_cast<const float4*>(x + (size_t)i * 4);
        xh[i * 2]     = __floats2half2_rn(f.x, f.y);
        xh[i * 2 + 1] = __floats2half2_rn(f.z, f.w);
    }
}

// ---------------- K5: fp16 gather — one wave per node, 2 edges/iter ----------------
// lane = h*32 + c: h = edge-of-pair (0/1), c = half2 column (features 2c,2c+1)
__global__ void gather_h_kernel(const __half2* __restrict__ xh,
                                const int* __restrict__ row_ptr,
                                const int* __restrict__ csr_src,
                                const float* __restrict__ dis,
                                float* __restrict__ out, int N) {
    int wid = (int)((blockIdx.x * (long long)blockDim.x + threadIdx.x) >> 6);
    int lane = threadIdx.x & 63;
    if (wid >= N) return;
    const int h = lane >> 5;        // which edge of the pair
    const int c = lane & 31;        // half2 column
    int beg = row_ptr[wid];
    int end = row_ptr[wid + 1];
    float dd = dis[wid];
    float accx = 0.0f, accy = 0.0f;
    int cnt = end - beg;
    int k = beg;
    int n8 = beg + (cnt & ~7);
    for (; k < n8; k += 8) {
        int s0 = __builtin_nontemporal_load(csr_src + k + 0 + h);
        int s1 = __builtin_nontemporal_load(csr_src + k + 2 + h);
        int s2 = __builtin_nontemporal_load(csr_src + k + 4 + h);
        int s3 = __builtin_nontemporal_load(csr_src + k + 6 + h);
        __half2 v0 = xh[(size_t)s0 * 32 + c];
        __half2 v1 = xh[(size_t)s1 * 32 + c];
        __half2 v2 = xh[(size_t)s2 * 32 + c];
        __half2 v3 = xh[(size_t)s3 * 32 + c];
        float w0 = dis[s0] * dd, w1 = dis[s1] * dd;
        float w2 = dis[s2] * dd, w3 = dis[s3] * dd;
        float2 f0 = __half22float2(v0);
        float2 f1 = __half22float2(v1);
        float2 f2 = __half22float2(v2);
        float2 f3 = __half22float2(v3);
        accx += f0.x * w0 + f1.x * w1 + f2.x * w2 + f3.x * w3;
        accy += f0.y * w0 + f1.y * w1 + f2.y * w2 + f3.y * w3;
    }
    int n2 = beg + (cnt & ~1);
    for (; k < n2; k += 2) {
        int s0 = __builtin_nontemporal_load(csr_src + k + h);
        __half2 v0 = xh[(size_t)s0 * 32 + c];
        float w0 = dis[s0] * dd;
        float2 f0 = __half22float2(v0);
        accx += f0.x * w0;
        accy += f0.y * w0;
    }
    if (k < end && h == 0) {        // odd leftover edge: lower half only
        int s0 = __builtin_nontemporal_load(csr_src + k);
        __half2 v0 = xh[(size_t)s0 * 32 + c];
        float w0 = dis[s0] * dd;
        float2 f0 = __half22float2(v0);
        accx += f0.x * w0;
        accy += f0.y * w0;
    }
    // cross-half reduce, then lanes 0-31 store 2 floats (contiguous 256B/wave)
    accx += __shfl_xor(accx, 32);
    accy += __shfl_xor(accy, 32);
    if (h == 0) {
        float* o = out + (size_t)wid * DFEAT + 2 * c;
        __builtin_nontemporal_store(accx, o);
        __builtin_nontemporal_store(accy, o + 1);
    }
}

// ---------------- K5-alt: f32 gather (used if xh can't overlay records) ----------------
__global__ void gather_kernel(const float* __restrict__ x,
                              const int* __restrict__ row_ptr,
                              const int* __restrict__ csr_src,
                              const float* __restrict__ dis,
                              float* __restrict__ out, int N) {
    int wid = (int)((blockIdx.x * (long long)blockDim.x + threadIdx.x) >> 6);
    int lane = threadIdx.x & 63;
    if (wid >= N) return;
    int beg = row_ptr[wid];
    int end = row_ptr[wid + 1];
    float dd = dis[wid];
    float acc = 0.0f;
    int k = beg;
    int n4 = beg + ((end - beg) & ~3);
    for (; k < n4; k += 4) {
        int s0 = __builtin_nontemporal_load(csr_src + k);
        int s1 = __builtin_nontemporal_load(csr_src + k + 1);
        int s2 = __builtin_nontemporal_load(csr_src + k + 2);
        int s3 = __builtin_nontemporal_load(csr_src + k + 3);
        float w0 = dis[s0], w1 = dis[s1], w2 = dis[s2], w3 = dis[s3];
        float v0 = x[(size_t)s0 * DFEAT + lane];
        float v1 = x[(size_t)s1 * DFEAT + lane];
        float v2 = x[(size_t)s2 * DFEAT + lane];
        float v3 = x[(size_t)s3 * DFEAT + lane];
        acc += v0 * (w0 * dd) + v1 * (w1 * dd) + v2 * (w2 * dd) + v3 * (w3 * dd);
    }
    for (; k < end; ++k) {
        int s0 = __builtin_nontemporal_load(csr_src + k);
        acc += x[(size_t)s0 * DFEAT + lane] * (dis[s0] * dd);
    }
    __builtin_nontemporal_store(acc, &out[(size_t)wid * DFEAT + lane]);
}

// ---------------- fallback (atomic scatter) if ws too small ----------------
__global__ void fb_deg_kernel(const int* __restrict__ dst,
                              float* __restrict__ deg, int E, int N) {
    int e = blockIdx.x * blockDim.x + threadIdx.x;
    if (e < E) {
        unsigned d = (unsigned)dst[e];
        if (d < (unsigned)N) unsafeAtomicAdd(&deg[d], 1.0f);
    }
}
__global__ void fb_dis_kernel(float* __restrict__ deg, int N) {
    int i = blockIdx.x * blockDim.x + threadIdx.x;
    if (i < N) {
        float d = deg[i];
        deg[i] = (d > 0.0f) ? rsqrtf(d) : 0.0f;
    }
}
__global__ void fb_scatter_kernel(const float* __restrict__ x,
                                  const int* __restrict__ src,
                                  const int* __restrict__ dst,
                                  const float* __restrict__ dis,
                                  float* __restrict__ out, int E, int N) {
    long long t = (long long)blockIdx.x * blockDim.x + threadIdx.x;
    int e = (int)(t >> 4);
    int c = (int)(t & 15);
    if (e >= E) return;
    unsigned s = (unsigned)src[e];
    unsigned d = (unsigned)dst[e];
    if (s >= (unsigned)N || d >= (unsigned)N) return;
    float norm = dis[s] * dis[d];
    const float4 v = *reinterpret_cast<const float4*>(x + (size_t)s * DFEAT + c * 4);
    float* o = out + (size_t)d * DFEAT + c * 4;
    unsafeAtomicAdd(o + 0, v.x * norm);
    unsafeAtomicAdd(o + 1, v.y * norm);
    unsafeAtomicAdd(o + 2, v.z * norm);
    unsafeAtomicAdd(o + 3, v.w * norm);
}

extern "C" void kernel_launch(void* const* d_in, const int* in_sizes, int n_in,
                              void* d_out, int out_size, void* d_ws, size_t ws_size,
                              hipStream_t stream) {
    const float* x  = (const float*)d_in[0];
    const int*   ei = (const int*)d_in[1];   // harness delivers integer inputs as int32

    const int N = in_sizes[0] / DFEAT;        // 100000
    const int E = in_sizes[1] / 2;            // 1600000
    const int* src = ei;                      // row 0
    const int* dst = ei + E;                  // row 1

    float* out = (float*)d_out;

    const int NB = (N + BIN_W - 1) / BIN_W;   // bins (256 for N=100000)
    const int NT = (E + TILE - 1) / TILE;     // tiles (391 for E=1.6M)

    // workspace layout (16B-aligned chunks)
    char* base = (char*)d_ws;
    size_t off = 0;
    auto alloc = [&](size_t bytes) { void* p = base + off; off += (bytes + 15) & ~(size_t)15; return p; };
    u64*   records  = (u64*)alloc((size_t)NT * TILE * 8);
    int*   dir      = (int*)alloc((size_t)NT * DIRW * 4);
    int*   bin_cnt  = (int*)alloc(256 * 4);
    int*   bin_base = (int*)alloc(257 * 4);
    float* dis      = (float*)alloc((size_t)N * 4);
    int*   row_ptr  = (int*)alloc((size_t)(N + 1) * 4);
    int*   csr_src  = (int*)alloc((size_t)E * 4);

    const bool ok = (off <= ws_size) && (NB <= 256) && (NT <= MAX_NT);
    // xh overlays the records buffer (dead after csr_build; stream is serial)
    const bool xh_fits = (size_t)NT * TILE * 8 >= (size_t)N * DFEAT * 2;

    if (ok) {
        hipMemsetAsync(bin_cnt, 0, 256 * 4, stream);

        bin_kernel<<<NT, K1_THREADS, 0, stream>>>(src, dst, records, dir, bin_cnt, E, N);
        scan_bins_kernel<<<1, 256, 0, stream>>>(bin_cnt, bin_base, row_ptr, N, NB);
        csr_build_kernel<<<NB, K3_THREADS, 0, stream>>>(records, dir, bin_base, dis, row_ptr, csr_src, N, NT);

        long long total = (long long)N * 64;
        int gb = (int)((total + 255) / 256);
        if (xh_fits) {
            __half2* xh = (__half2*)records;
            int total4 = N * DFEAT / 4;
            stage_xh_kernel<<<(total4 + 255) / 256, 256, 0, stream>>>(x, xh, total4);
            gather_h_kernel<<<gb, 256, 0, stream>>>(xh, row_ptr, csr_src, dis, out, N);
        } else {
            gather_kernel<<<gb, 256, 0, stream>>>(x, row_ptr, csr_src, dis, out, N);
        }
    } else {
        // fallback: atomic scatter (needs only N floats of ws)
        float* deg = (float*)d_ws;
        hipMemsetAsync(deg, 0, (size_t)N * 4, stream);
        hipMemsetAsync(out, 0, (size_t)out_size * 4, stream);
        int eb = (E + 255) / 256;
        fb_deg_kernel<<<eb, 256, 0, stream>>>(dst, deg, E, N);
        int nb = (N + 255) / 256;
        fb_dis_kernel<<<nb, 256, 0, stream>>>(deg, N);
        long long total = (long long)E * 16;
        int sb = (int)((total + 255) / 256);
        fb_scatter_kernel<<<sb, 256, 0, stream>>>(x, src, dst, deg, out, E, N);
    }
}

// Round 12
// 118.974 us; speedup vs baseline: 5.6178x; 1.0522x over previous
//
#include <hip/hip_runtime.h>
#include <hip/hip_fp16.h>

// LGConv: out = D^{-1/2} A D^{-1/2} x
// x: f32 [N, 64]; edge_index: int32 on device (harness downcasts int64), [2, E]
//
// Pipeline:
//  K1 bin_kernel: per 4096-edge tile, LDS count/scan/reorder by dst-bin (256
//     bins of BIN_W nodes), sequential flush of {dst,src} records + per-tile
//     directory + per-bin totals (global atomics).
//  K3 csr_build: one 1024-thread block per bin. Fused bin_base scan; loads
//     the bin's ~50KB of records into LDS ONCE (4-runs-per-wave copy), then
//     histogram -> dis + row_ptr + cur, scatter csr_src (L2-merged window),
//     all from LDS. Global two-pass fallback if bin overflows CAP.
//  K4 stage_xs: xs[s] = dis[s] * x[s] in fp16 (__half2), overlaid on dead
//     records buffer. Gather then needs no per-edge dis load.
//  K5 gather_hs: one wave per dst node; lane = (edge-of-pair, half2-col):
//     2 edges/iter, 128B per edge-row, unroll x4, cross-half shfl reduce,
//     out = dis[dst] * sum, scalar nontemporal stores.

#define DFEAT 64
#define BIN_W 391          // nodes per bin; NB = ceil(N/BIN_W) must be <= 256
#define TILE 4096          // edges per K1 block
#define K1_THREADS 256
#define EPT (TILE / K1_THREADS)   // 16
#define DIRW 257
#define K3_THREADS 1024
#define MAX_NT 512         // run-bound cache capacity; NT must be <= this
#define CAP 12288          // LDS record capacity (mean 6250, +76 sigma)

typedef unsigned long long u64;

// ---------------- K1: LDS-reordered binning ----------------
__global__ __launch_bounds__(K1_THREADS)
void bin_kernel(const int* __restrict__ src, const int* __restrict__ dst,
                u64* __restrict__ records, int* __restrict__ dir,
                int* __restrict__ bin_cnt, int E, int N) {
    __shared__ int cnt[256];
    __shared__ int off[DIRW];
    __shared__ int rnk[256];
    __shared__ u64 buf[TILE];

    const int t    = blockIdx.x;
    const int base = t * TILE;
    const int tid  = threadIdx.x;

    cnt[tid] = 0;
    rnk[tid] = 0;
    __syncthreads();

    // phase A: load + count (validates indices; keep records in regs)
    u64 rec[EPT];
    int myb[EPT];
    #pragma unroll
    for (int i = 0; i < EPT; ++i) {
        int e = base + tid + i * K1_THREADS;
        int b = -1;
        u64 r = 0;
        if (e < E) {
            unsigned d = (unsigned)dst[e];
            unsigned s = (unsigned)src[e];
            if (d < (unsigned)N && s < (unsigned)N) {
                b = (int)(d / BIN_W);
                r = ((u64)d << 32) | (u64)s;
            }
        }
        myb[i] = b;
        rec[i] = r;
        if (b >= 0) atomicAdd(&cnt[b], 1);
    }
    __syncthreads();

    // phase B: exclusive scan of cnt -> off
    int v = cnt[tid];
    off[tid] = v;
    __syncthreads();
    for (int d = 1; d < 256; d <<= 1) {
        int add = (tid >= d) ? off[tid - d] : 0;
        __syncthreads();
        off[tid] += add;
        __syncthreads();
    }
    int incl = off[tid];
    __syncthreads();
    off[tid] = incl - v;
    if (tid == 255) off[256] = incl;
    __syncthreads();

    // directory row + per-bin totals
    dir[t * DIRW + tid] = off[tid];
    if (tid == 0) dir[t * DIRW + 256] = off[256];
    if (v > 0) atomicAdd(&bin_cnt[tid], v);

    // phase C: place records into LDS at binned positions
    #pragma unroll
    for (int i = 0; i < EPT; ++i) {
        int b = myb[i];
        if (b >= 0) {
            int r = atomicAdd(&rnk[b], 1);
            buf[off[b] + r] = rec[i];
        }
    }
    __syncthreads();

    // phase D: sequential coalesced flush
    int total = off[256];
    for (int i = tid; i < total; i += K1_THREADS)
        records[(size_t)base + i] = buf[i];
}

// ---------------- K3: per-bin CSR build, single LDS-resident pass ----------------
__global__ __launch_bounds__(K3_THREADS)
void csr_build_kernel(const u64* __restrict__ records,
                      const int* __restrict__ dir,
                      const int* __restrict__ bin_cnt,
                      float* __restrict__ dis,
                      int* __restrict__ row_ptr,
                      int* __restrict__ csr_src, int N, int NT, int NB) {
    __shared__ u64 ldsrec[CAP];     // 96KB
    __shared__ int deg[512];        // scratch: bin-scan, len-scan, histogram
    __shared__ int cur[BIN_W];
    __shared__ int sbeg[MAX_NT];
    __shared__ int send[MAX_NT];
    __shared__ int lofs[MAX_NT];
    __shared__ int sh_total, sh_gb0;

    const int b  = blockIdx.x;
    const int lo = b * BIN_W;
    const int nodes = min(BIN_W, N - lo);
    const int tid = threadIdx.x;
    const int wave = tid >> 6, lane = tid & 63;

    // --- fused bin_base scan (deg as scratch) ---
    int bv = 0;
    if (tid < 512) { bv = (tid < NB) ? bin_cnt[tid] : 0; deg[tid] = bv; }
    __syncthreads();
    for (int d = 1; d < 512; d <<= 1) {
        int a = (tid < 512 && tid >= d) ? deg[tid - d] : 0;
        __syncthreads();
        if (tid < 512) deg[tid] += a;
        __syncthreads();
    }
    if (tid == b) sh_gb0 = deg[tid] - bv;           // exclusive prefix for bin b
    if (b == 0 && tid == 0) row_ptr[N] = deg[NB - 1];
    __syncthreads();                                 // protect deg before reuse

    // --- run bounds + LDS-offset scan ---
    for (int t = tid; t < NT; t += K3_THREADS) {
        sbeg[t] = dir[t * DIRW + b];
        send[t] = dir[t * DIRW + b + 1];
    }
    __syncthreads();
    if (tid < 512) deg[tid] = (tid < NT) ? (send[tid] - sbeg[tid]) : 0;
    __syncthreads();
    for (int d = 1; d < 512; d <<= 1) {
        int a = (tid < 512 && tid >= d) ? deg[tid - d] : 0;
        __syncthreads();
        if (tid < 512) deg[tid] += a;
        __syncthreads();
    }
    if (tid < NT) lofs[tid] = deg[tid] - (send[tid] - sbeg[tid]);  // exclusive
    if (tid == 0) sh_total = deg[511];
    __syncthreads();

    const int total = sh_total;
    const bool fits = (total <= CAP);

    // --- copy records into LDS: 4 runs per wave (16 lanes each) ---
    if (fits) {
        for (int rb = wave * 4; rb < NT; rb += 64) {
            int r = rb + (lane >> 4);
            if (r < NT) {
                int g0  = r * TILE + sbeg[r];
                int l0  = lofs[r];
                int len = send[r] - sbeg[r];
                for (int k = (lane & 15); k < len; k += 16)
                    ldsrec[l0 + k] = records[g0 + k];
            }
        }
    }
    __syncthreads();

    // --- histogram ---
    if (tid < 512) deg[tid] = 0;
    __syncthreads();
    if (fits) {
        for (int i = tid; i < total; i += K3_THREADS)
            atomicAdd(&deg[(int)(ldsrec[i] >> 32) - lo], 1);
    } else {
        for (int t = wave; t < NT; t += 16) {
            int s = sbeg[t], e = send[t], gb = t * TILE;
            for (int k = s + lane; k < e; k += 64)
                atomicAdd(&deg[(int)(records[gb + k] >> 32) - lo], 1);
        }
    }
    __syncthreads();

    // --- dis slice ---
    if (tid < nodes) {
        int c = deg[tid];
        dis[lo + tid] = (c > 0) ? rsqrtf((float)c) : 0.0f;
    }

    // --- scan degrees -> row_ptr + cursors ---
    int v0 = (tid < 512) ? deg[tid] : 0;
    __syncthreads();
    for (int d = 1; d < 512; d <<= 1) {
        int a = (tid < 512 && tid >= d) ? deg[tid - d] : 0;
        __syncthreads();
        if (tid < 512) deg[tid] += a;
        __syncthreads();
    }
    if (tid < nodes) {
        int g = sh_gb0 + deg[tid] - v0;
        row_ptr[lo + tid] = g;
        cur[tid] = g;
    }
    __syncthreads();

    // --- scatter src into the bin's private csr window ---
    if (fits) {
        for (int i = tid; i < total; i += K3_THREADS) {
            u64 r = ldsrec[i];
            int p = atomicAdd(&cur[(int)(r >> 32) - lo], 1);
            csr_src[p] = (int)(unsigned)r;
        }
    } else {
        for (int t = wave; t < NT; t += 16) {
            int s = sbeg[t], e = send[t], gb = t * TILE;
            for (int k = s + lane; k < e; k += 64) {
                u64 r = records[gb + k];
                int p = atomicAdd(&cur[(int)(r >> 32) - lo], 1);
                csr_src[p] = (int)(unsigned)r;
            }
        }
    }
}

// ---------------- K4: stage xs = dis[s] * x[s] -> fp16 (__half2 pairs) ----------------
__global__ __launch_bounds__(256)
void stage_xs_kernel(const float* __restrict__ x, const float* __restrict__ dis,
                     __half2* __restrict__ xs, int total4 /* N*DFEAT/4 */) {
    int i = blockIdx.x * blockDim.x + threadIdx.x;
    if (i < total4) {
        float w = dis[i >> 4];   // 16 float4 per node
        float4 f = *reinterpret_cast<const float4*>(x + (size_t)i * 4);
        xs[i * 2]     = __floats2half2_rn(f.x * w, f.y * w);
        xs[i * 2 + 1] = __floats2half2_rn(f.z * w, f.w * w);
    }
}

// ---------------- K5: gather — one wave per node, 2 edges/iter, prescaled ----------------
// lane = h*32 + c: h = edge-of-pair (0/1), c = half2 column (features 2c,2c+1)
__global__ void gather_hs_kernel(const __half2* __restrict__ xs,
                                 const int* __restrict__ row_ptr,
                                 const int* __restrict__ csr_src,
                                 const float* __restrict__ dis,
                                 float* __restrict__ out, int N) {
    int wid = (int)((blockIdx.x * (long long)blockDim.x + threadIdx.x) >> 6);
    int lane = threadIdx.x & 63;
    if (wid >= N) return;
    const int h = lane >> 5;
    const int c = lane & 31;
    int beg = row_ptr[wid];
    int end = row_ptr[wid + 1];
    float accx = 0.0f, accy = 0.0f;
    int cnt = end - beg;
    int k = beg;
    int n8 = beg + (cnt & ~7);
    for (; k < n8; k += 8) {
        int s0 = __builtin_nontemporal_load(csr_src + k + 0 + h);
        int s1 = __builtin_nontemporal_load(csr_src + k + 2 + h);
        int s2 = __builtin_nontemporal_load(csr_src + k + 4 + h);
        int s3 = __builtin_nontemporal_load(csr_src + k + 6 + h);
        __half2 v0 = xs[(size_t)s0 * 32 + c];
        __half2 v1 = xs[(size_t)s1 * 32 + c];
        __half2 v2 = xs[(size_t)s2 * 32 + c];
        __half2 v3 = xs[(size_t)s3 * 32 + c];
        float2 f0 = __half22float2(v0);
        float2 f1 = __half22float2(v1);
        float2 f2 = __half22float2(v2);
        float2 f3 = __half22float2(v3);
        accx += f0.x + f1.x + f2.x + f3.x;
        accy += f0.y + f1.y + f2.y + f3.y;
    }
    int n2 = beg + (cnt & ~1);
    for (; k < n2; k += 2) {
        int s0 = __builtin_nontemporal_load(csr_src + k + h);
        float2 f0 = __half22float2(xs[(size_t)s0 * 32 + c]);
        accx += f0.x;
        accy += f0.y;
    }
    if (k < end && h == 0) {        // odd leftover edge: lower half only
        int s0 = __builtin_nontemporal_load(csr_src + k);
        float2 f0 = __half22float2(xs[(size_t)s0 * 32 + c]);
        accx += f0.x;
        accy += f0.y;
    }
    accx += __shfl_xor(accx, 32);
    accy += __shfl_xor(accy, 32);
    if (h == 0) {
        float dd = dis[wid];
        float* o = out + (size_t)wid * DFEAT + 2 * c;
        __builtin_nontemporal_store(accx * dd, o);
        __builtin_nontemporal_store(accy * dd, o + 1);
    }
}

// ---------------- fallback (atomic scatter) if ws too small ----------------
__global__ void fb_deg_kernel(const int* __restrict__ dst,
                              float* __restrict__ deg, int E, int N) {
    int e = blockIdx.x * blockDim.x + threadIdx.x;
    if (e < E) {
        unsigned d = (unsigned)dst[e];
        if (d < (unsigned)N) unsafeAtomicAdd(&deg[d], 1.0f);
    }
}
__global__ void fb_dis_kernel(float* __restrict__ deg, int N) {
    int i = blockIdx.x * blockDim.x + threadIdx.x;
    if (i < N) {
        float d = deg[i];
        deg[i] = (d > 0.0f) ? rsqrtf(d) : 0.0f;
    }
}
__global__ void fb_scatter_kernel(const float* __restrict__ x,
                                  const int* __restrict__ src,
                                  const int* __restrict__ dst,
                                  const float* __restrict__ dis,
                                  float* __restrict__ out, int E, int N) {
    long long t = (long long)blockIdx.x * blockDim.x + threadIdx.x;
    int e = (int)(t >> 4);
    int c = (int)(t & 15);
    if (e >= E) return;
    unsigned s = (unsigned)src[e];
    unsigned d = (unsigned)dst[e];
    if (s >= (unsigned)N || d >= (unsigned)N) return;
    float norm = dis[s] * dis[d];
    const float4 v = *reinterpret_cast<const float4*>(x + (size_t)s * DFEAT + c * 4);
    float* o = out + (size_t)d * DFEAT + c * 4;
    unsafeAtomicAdd(o + 0, v.x * norm);
    unsafeAtomicAdd(o + 1, v.y * norm);
    unsafeAtomicAdd(o + 2, v.z * norm);
    unsafeAtomicAdd(o + 3, v.w * norm);
}

extern "C" void kernel_launch(void* const* d_in, const int* in_sizes, int n_in,
                              void* d_out, int out_size, void* d_ws, size_t ws_size,
                              hipStream_t stream) {
    const float* x  = (const float*)d_in[0];
    const int*   ei = (const int*)d_in[1];   // harness delivers integer inputs as int32

    const int N = in_sizes[0] / DFEAT;        // 100000
    const int E = in_sizes[1] / 2;            // 1600000
    const int* src = ei;                      // row 0
    const int* dst = ei + E;                  // row 1

    float* out = (float*)d_out;

    const int NB = (N + BIN_W - 1) / BIN_W;   // bins (256 for N=100000)
    const int NT = (E + TILE - 1) / TILE;     // tiles (391 for E=1.6M)

    // workspace layout (16B-aligned chunks)
    char* base = (char*)d_ws;
    size_t off = 0;
    auto alloc = [&](size_t bytes) { void* p = base + off; off += (bytes + 15) & ~(size_t)15; return p; };
    u64*   records  = (u64*)alloc((size_t)NT * TILE * 8);
    int*   dir      = (int*)alloc((size_t)NT * DIRW * 4);
    int*   bin_cnt  = (int*)alloc(256 * 4);
    float* dis      = (float*)alloc((size_t)N * 4);
    int*   row_ptr  = (int*)alloc((size_t)(N + 1) * 4);
    int*   csr_src  = (int*)alloc((size_t)E * 4);

    const bool ok = (off <= ws_size) && (NB <= 256) && (NT <= MAX_NT);
    // xs overlays the records buffer (dead after csr_build; stream is serial)
    const bool xs_fits = (size_t)NT * TILE * 8 >= (size_t)N * DFEAT * 2;

    if (ok && xs_fits) {
        hipMemsetAsync(bin_cnt, 0, 256 * 4, stream);

        bin_kernel<<<NT, K1_THREADS, 0, stream>>>(src, dst, records, dir, bin_cnt, E, N);
        csr_build_kernel<<<NB, K3_THREADS, 0, stream>>>(records, dir, bin_cnt, dis,
                                                        row_ptr, csr_src, N, NT, NB);

        __half2* xs = (__half2*)records;
        int total4 = N * DFEAT / 4;
        stage_xs_kernel<<<(total4 + 255) / 256, 256, 0, stream>>>(x, dis, xs, total4);

        long long total = (long long)N * 64;
        int gb = (int)((total + 255) / 256);
        gather_hs_kernel<<<gb, 256, 0, stream>>>(xs, row_ptr, csr_src, dis, out, N);
    } else {
        // fallback: atomic scatter (needs only N floats of ws)
        float* deg = (float*)d_ws;
        hipMemsetAsync(deg, 0, (size_t)N * 4, stream);
        hipMemsetAsync(out, 0, (size_t)out_size * 4, stream);
        int eb = (E + 255) / 256;
        fb_deg_kernel<<<eb, 256, 0, stream>>>(dst, deg, E, N);
        int nb = (N + 255) / 256;
        fb_dis_kernel<<<nb, 256, 0, stream>>>(deg, N);
        long long total = (long long)E * 16;
        int sb = (int)((total + 255) / 256);
        fb_scatter_kernel<<<sb, 256, 0, stream>>>(x, src, dst, deg, out, E, N);
    }
}

// Round 13
// 113.650 us; speedup vs baseline: 5.8810x; 1.0468x over previous
//
#include <hip/hip_runtime.h>
#include <hip/hip_fp16.h>

// LGConv: out = D^{-1/2} A D^{-1/2} x
// x: f32 [N, 64]; edge_index: int32 on device (harness downcasts int64), [2, E]
//
// Pipeline:
//  K1 bin_kernel: per 8192-edge tile, LDS count/scan/reorder by dst-bin (256
//     bins of BIN_W nodes), sequential flush of packed 4B records
//     ((dloc<<23)|src) + per-tile directory + per-bin totals.
//  K3 csr_build: one 1024-thread block per bin. Fused bin_base scan; copies
//     the bin's ~25KB of records into LDS once (half-wave per run, runs are
//     ~full cache lines), histogram -> dis + row_ptr + cur, scatter csr_src
//     into the bin's private window (L2-merged). Global fallback if > CAP.
//  K4 stage_xs: xs[s] = dis[s] * x[s] in fp16 (__half2), overlaid on dead
//     records region (region sized max(records, xs)).
//  K5 gather_q: one wave per dst node; lane = (q=edge-of-quad, c8=8B-col):
//     4 edges per xs instruction (8B/lane), unroll 2 -> 8 edges/iter,
//     cross-quad shfl_xor reduce, float4 nontemporal store.

#define DFEAT 64
#define BIN_W 391          // nodes per bin; NB = ceil(N/BIN_W) must be <= 256
#define TILE 8192          // edges per K1 block
#define K1_THREADS 256
#define EPT (TILE / K1_THREADS)   // 32
#define DIRW 257
#define K3_THREADS 1024
#define MAX_NT 512         // run-bound cache capacity; NT must be <= this
#define CAP 8192           // LDS record capacity (mean 6250, +24 sigma)

typedef unsigned long long u64;
typedef unsigned int u32;
typedef float f4v __attribute__((ext_vector_type(4)));

// ---------------- K1: LDS-reordered binning, packed 4B records ----------------
__global__ __launch_bounds__(K1_THREADS)
void bin_kernel(const int* __restrict__ src, const int* __restrict__ dst,
                u32* __restrict__ records, int* __restrict__ dir,
                int* __restrict__ bin_cnt, int E, int N) {
    __shared__ int cnt[256];
    __shared__ int off[DIRW];
    __shared__ int rnk[256];
    __shared__ u32 buf[TILE];

    const int t    = blockIdx.x;
    const int base = t * TILE;
    const int tid  = threadIdx.x;

    cnt[tid] = 0;
    rnk[tid] = 0;
    __syncthreads();

    // phase A: load + count (validates indices; keep packed records in regs)
    u32 rec[EPT];
    int myb[EPT];
    #pragma unroll
    for (int i = 0; i < EPT; ++i) {
        int e = base + tid + i * K1_THREADS;
        int b = -1;
        u32 r = 0;
        if (e < E) {
            unsigned d = (unsigned)dst[e];
            unsigned s = (unsigned)src[e];
            if (d < (unsigned)N && s < (unsigned)N) {
                b = (int)(d / BIN_W);
                r = ((d - (unsigned)b * BIN_W) << 23) | s;   // dloc<9b> | src<23b>
            }
        }
        myb[i] = b;
        rec[i] = r;
        if (b >= 0) atomicAdd(&cnt[b], 1);
    }
    __syncthreads();

    // phase B: exclusive scan of cnt -> off
    int v = cnt[tid];
    off[tid] = v;
    __syncthreads();
    for (int d = 1; d < 256; d <<= 1) {
        int add = (tid >= d) ? off[tid - d] : 0;
        __syncthreads();
        off[tid] += add;
        __syncthreads();
    }
    int incl = off[tid];
    __syncthreads();
    off[tid] = incl - v;
    if (tid == 255) off[256] = incl;
    __syncthreads();

    // directory row + per-bin totals
    dir[t * DIRW + tid] = off[tid];
    if (tid == 0) dir[t * DIRW + 256] = off[256];
    if (v > 0) atomicAdd(&bin_cnt[tid], v);

    // phase C: place records into LDS at binned positions
    #pragma unroll
    for (int i = 0; i < EPT; ++i) {
        int b = myb[i];
        if (b >= 0) {
            int r = atomicAdd(&rnk[b], 1);
            buf[off[b] + r] = rec[i];
        }
    }
    __syncthreads();

    // phase D: sequential coalesced flush
    int total = off[256];
    for (int i = tid; i < total; i += K1_THREADS)
        records[(size_t)base + i] = buf[i];
}

// ---------------- K3: per-bin CSR build, single LDS-resident pass ----------------
__global__ __launch_bounds__(K3_THREADS)
void csr_build_kernel(const u32* __restrict__ records,
                      const int* __restrict__ dir,
                      const int* __restrict__ bin_cnt,
                      float* __restrict__ dis,
                      int* __restrict__ row_ptr,
                      int* __restrict__ csr_src, int N, int NT, int NB) {
    __shared__ u32 ldsrec[CAP];     // 32KB
    __shared__ int deg[512];        // scratch: bin-scan, len-scan, histogram
    __shared__ int cur[BIN_W];
    __shared__ int sbeg[MAX_NT];
    __shared__ int send[MAX_NT];
    __shared__ int lofs[MAX_NT];
    __shared__ int sh_total, sh_gb0;

    const int b  = blockIdx.x;
    const int lo = b * BIN_W;
    const int nodes = min(BIN_W, N - lo);
    const int tid = threadIdx.x;
    const int wave = tid >> 6, lane = tid & 63;

    // --- fused bin_base scan (deg as scratch) ---
    int bv = 0;
    if (tid < 512) { bv = (tid < NB) ? bin_cnt[tid] : 0; deg[tid] = bv; }
    __syncthreads();
    for (int d = 1; d < 512; d <<= 1) {
        int a = (tid < 512 && tid >= d) ? deg[tid - d] : 0;
        __syncthreads();
        if (tid < 512) deg[tid] += a;
        __syncthreads();
    }
    if (tid == b) sh_gb0 = deg[tid] - bv;           // exclusive prefix for bin b
    if (b == 0 && tid == 0) row_ptr[N] = deg[NB - 1];
    __syncthreads();                                 // protect deg before reuse

    // --- run bounds + LDS-offset scan ---
    for (int t = tid; t < NT; t += K3_THREADS) {
        sbeg[t] = dir[t * DIRW + b];
        send[t] = dir[t * DIRW + b + 1];
    }
    __syncthreads();
    if (tid < 512) deg[tid] = (tid < NT) ? (send[tid] - sbeg[tid]) : 0;
    __syncthreads();
    for (int d = 1; d < 512; d <<= 1) {
        int a = (tid < 512 && tid >= d) ? deg[tid - d] : 0;
        __syncthreads();
        if (tid < 512) deg[tid] += a;
        __syncthreads();
    }
    if (tid < NT) lofs[tid] = deg[tid] - (send[tid] - sbeg[tid]);  // exclusive
    if (tid == 0) sh_total = deg[511];
    __syncthreads();

    const int total = sh_total;
    const bool fits = (total <= CAP);

    // --- copy records into LDS: 2 runs per wave (32 lanes each) ---
    if (fits) {
        for (int rb = wave * 2; rb < NT; rb += 32) {
            int r = rb + (lane >> 5);
            if (r < NT) {
                int g0  = r * TILE + sbeg[r];
                int l0  = lofs[r];
                int len = send[r] - sbeg[r];
                for (int k = (lane & 31); k < len; k += 32)
                    ldsrec[l0 + k] = records[g0 + k];
            }
        }
    }
    __syncthreads();

    // --- histogram ---
    if (tid < 512) deg[tid] = 0;
    __syncthreads();
    if (fits) {
        for (int i = tid; i < total; i += K3_THREADS)
            atomicAdd(&deg[ldsrec[i] >> 23], 1);
    } else {
        for (int t = wave; t < NT; t += 16) {
            int s = sbeg[t], e = send[t], gb = t * TILE;
            for (int k = s + lane; k < e; k += 64)
                atomicAdd(&deg[records[gb + k] >> 23], 1);
        }
    }
    __syncthreads();

    // --- dis slice ---
    if (tid < nodes) {
        int c = deg[tid];
        dis[lo + tid] = (c > 0) ? rsqrtf((float)c) : 0.0f;
    }

    // --- scan degrees -> row_ptr + cursors ---
    int v0 = (tid < 512) ? deg[tid] : 0;
    __syncthreads();
    for (int d = 1; d < 512; d <<= 1) {
        int a = (tid < 512 && tid >= d) ? deg[tid - d] : 0;
        __syncthreads();
        if (tid < 512) deg[tid] += a;
        __syncthreads();
    }
    if (tid < nodes) {
        int g = sh_gb0 + deg[tid] - v0;
        row_ptr[lo + tid] = g;
        cur[tid] = g;
    }
    __syncthreads();

    // --- scatter src into the bin's private csr window ---
    if (fits) {
        for (int i = tid; i < total; i += K3_THREADS) {
            u32 r = ldsrec[i];
            int p = atomicAdd(&cur[r >> 23], 1);
            csr_src[p] = (int)(r & 0x7FFFFF);
        }
    } else {
        for (int t = wave; t < NT; t += 16) {
            int s = sbeg[t], e = send[t], gb = t * TILE;
            for (int k = s + lane; k < e; k += 64) {
                u32 r = records[gb + k];
                int p = atomicAdd(&cur[r >> 23], 1);
                csr_src[p] = (int)(r & 0x7FFFFF);
            }
        }
    }
}

// ---------------- K4: stage xs = dis[s] * x[s] -> fp16 (__half2 pairs) ----------------
__global__ __launch_bounds__(256)
void stage_xs_kernel(const float* __restrict__ x, const float* __restrict__ dis,
                     __half2* __restrict__ xs, int total4 /* N*DFEAT/4 */) {
    int i = blockIdx.x * blockDim.x + threadIdx.x;
    if (i < total4) {
        float w = dis[i >> 4];   // 16 float4 per node
        float4 f = *reinterpret_cast<const float4*>(x + (size_t)i * 4);
        xs[i * 2]     = __floats2half2_rn(f.x * w, f.y * w);
        xs[i * 2 + 1] = __floats2half2_rn(f.z * w, f.w * w);
    }
}

// ---------------- K5: gather — one wave per node, 4 edges per xs load ----------------
// lane = q*16 + c8: q = edge-of-quad (0..3), c8 = 8B column (features 4c8..4c8+3)
struct alignas(8) h4 { __half2 a, b; };

__global__ void gather_q_kernel(const h4* __restrict__ xs4,
                                const int* __restrict__ row_ptr,
                                const int* __restrict__ csr_src,
                                const float* __restrict__ dis,
                                float* __restrict__ out, int N) {
    int wid = (int)((blockIdx.x * (long long)blockDim.x + threadIdx.x) >> 6);
    int lane = threadIdx.x & 63;
    if (wid >= N) return;
    const int q  = lane >> 4;
    const int c8 = lane & 15;
    int beg = row_ptr[wid];
    int end = row_ptr[wid + 1];
    int cnt = end - beg;
    float a0 = 0.0f, a1 = 0.0f, a2 = 0.0f, a3 = 0.0f;
    int k = beg;
    int n8 = beg + (cnt & ~7);
    for (; k < n8; k += 8) {
        int sA = csr_src[k + q];
        int sB = csr_src[k + 4 + q];
        h4 vA = xs4[(size_t)sA * 16 + c8];
        h4 vB = xs4[(size_t)sB * 16 + c8];
        float2 fA0 = __half22float2(vA.a), fA1 = __half22float2(vA.b);
        float2 fB0 = __half22float2(vB.a), fB1 = __half22float2(vB.b);
        a0 += fA0.x + fB0.x;
        a1 += fA0.y + fB0.y;
        a2 += fA1.x + fB1.x;
        a3 += fA1.y + fB1.y;
    }
    if (k + 4 <= end) {
        int sA = csr_src[k + q];
        h4 vA = xs4[(size_t)sA * 16 + c8];
        float2 fA0 = __half22float2(vA.a), fA1 = __half22float2(vA.b);
        a0 += fA0.x; a1 += fA0.y; a2 += fA1.x; a3 += fA1.y;
        k += 4;
    }
    for (; k < end; ++k) {            // <=3 leftover edges: quad 0 only
        int s = csr_src[k];
        if (q == 0) {
            h4 v = xs4[(size_t)s * 16 + c8];
            float2 f0 = __half22float2(v.a), f1 = __half22float2(v.b);
            a0 += f0.x; a1 += f0.y; a2 += f1.x; a3 += f1.y;
        }
    }
    // reduce across the 4 quads (lane^16, lane^32)
    a0 += __shfl_xor(a0, 16); a1 += __shfl_xor(a1, 16);
    a2 += __shfl_xor(a2, 16); a3 += __shfl_xor(a3, 16);
    a0 += __shfl_xor(a0, 32); a1 += __shfl_xor(a1, 32);
    a2 += __shfl_xor(a2, 32); a3 += __shfl_xor(a3, 32);
    if (q == 0) {
        float dd = dis[wid];
        f4v o = { a0 * dd, a1 * dd, a2 * dd, a3 * dd };
        __builtin_nontemporal_store(o, (f4v*)(out + (size_t)wid * DFEAT + c8 * 4));
    }
}

// ---------------- fallback (atomic scatter) if ws too small ----------------
__global__ void fb_deg_kernel(const int* __restrict__ dst,
                              float* __restrict__ deg, int E, int N) {
    int e = blockIdx.x * blockDim.x + threadIdx.x;
    if (e < E) {
        unsigned d = (unsigned)dst[e];
        if (d < (unsigned)N) unsafeAtomicAdd(&deg[d], 1.0f);
    }
}
__global__ void fb_dis_kernel(float* __restrict__ deg, int N) {
    int i = blockIdx.x * blockDim.x + threadIdx.x;
    if (i < N) {
        float d = deg[i];
        deg[i] = (d > 0.0f) ? rsqrtf(d) : 0.0f;
    }
}
__global__ void fb_scatter_kernel(const float* __restrict__ x,
                                  const int* __restrict__ src,
                                  const int* __restrict__ dst,
                                  const float* __restrict__ dis,
                                  float* __restrict__ out, int E, int N) {
    long long t = (long long)blockIdx.x * blockDim.x + threadIdx.x;
    int e = (int)(t >> 4);
    int c = (int)(t & 15);
    if (e >= E) return;
    unsigned s = (unsigned)src[e];
    unsigned d = (unsigned)dst[e];
    if (s >= (unsigned)N || d >= (unsigned)N) return;
    float norm = dis[s] * dis[d];
    const float4 v = *reinterpret_cast<const float4*>(x + (size_t)s * DFEAT + c * 4);
    float* o = out + (size_t)d * DFEAT + c * 4;
    unsafeAtomicAdd(o + 0, v.x * norm);
    unsafeAtomicAdd(o + 1, v.y * norm);
    unsafeAtomicAdd(o + 2, v.z * norm);
    unsafeAtomicAdd(o + 3, v.w * norm);
}

extern "C" void kernel_launch(void* const* d_in, const int* in_sizes, int n_in,
                              void* d_out, int out_size, void* d_ws, size_t ws_size,
                              hipStream_t stream) {
    const float* x  = (const float*)d_in[0];
    const int*   ei = (const int*)d_in[1];   // harness delivers integer inputs as int32

    const int N = in_sizes[0] / DFEAT;        // 100000
    const int E = in_sizes[1] / 2;            // 1600000
    const int* src = ei;                      // row 0
    const int* dst = ei + E;                  // row 1

    float* out = (float*)d_out;

    const int NB = (N + BIN_W - 1) / BIN_W;   // bins (256 for N=100000)
    const int NT = (E + TILE - 1) / TILE;     // tiles (196 for E=1.6M)

    // workspace layout (16B-aligned chunks)
    char* base = (char*)d_ws;
    size_t off = 0;
    auto alloc = [&](size_t bytes) { void* p = base + off; off += (bytes + 15) & ~(size_t)15; return p; };
    size_t rec_bytes = (size_t)NT * TILE * 4;
    size_t xs_bytes  = (size_t)N * DFEAT * 2;
    size_t region    = rec_bytes > xs_bytes ? rec_bytes : xs_bytes;
    u32*   records  = (u32*)alloc(region);    // records, later overlaid by xs
    int*   dir      = (int*)alloc((size_t)NT * DIRW * 4);
    int*   bin_cnt  = (int*)alloc(256 * 4);
    float* dis      = (float*)alloc((size_t)N * 4);
    int*   row_ptr  = (int*)alloc((size_t)(N + 1) * 4);
    int*   csr_src  = (int*)alloc((size_t)E * 4);

    const bool ok = (off <= ws_size) && (NB <= 256) && (NT <= MAX_NT) &&
                    (N <= (1 << 23)) && (BIN_W <= 512);

    if (ok) {
        hipMemsetAsync(bin_cnt, 0, 256 * 4, stream);

        bin_kernel<<<NT, K1_THREADS, 0, stream>>>(src, dst, records, dir, bin_cnt, E, N);
        csr_build_kernel<<<NB, K3_THREADS, 0, stream>>>(records, dir, bin_cnt, dis,
                                                        row_ptr, csr_src, N, NT, NB);

        __half2* xs = (__half2*)records;      // overlay: records dead after K3
        int total4 = N * DFEAT / 4;
        stage_xs_kernel<<<(total4 + 255) / 256, 256, 0, stream>>>(x, dis, xs, total4);

        long long total = (long long)N * 64;
        int gb = (int)((total + 255) / 256);
        gather_q_kernel<<<gb, 256, 0, stream>>>((const h4*)xs, row_ptr, csr_src, dis, out, N);
    } else {
        // fallback: atomic scatter (needs only N floats of ws)
        float* deg = (float*)d_ws;
        hipMemsetAsync(deg, 0, (size_t)N * 4, stream);
        hipMemsetAsync(out, 0, (size_t)out_size * 4, stream);
        int eb = (E + 255) / 256;
        fb_deg_kernel<<<eb, 256, 0, stream>>>(dst, deg, E, N);
        int nb = (N + 255) / 256;
        fb_dis_kernel<<<nb, 256, 0, stream>>>(deg, N);
        long long total = (long long)E * 16;
        int sb = (int)((total + 255) / 256);
        fb_scatter_kernel<<<sb, 256, 0, stream>>>(x, src, dst, deg, out, E, N);
    }
}

// Round 14
// 106.807 us; speedup vs baseline: 6.2578x; 1.0641x over previous
//
#include <hip/hip_runtime.h>
#include <hip/hip_fp16.h>

// LGConv: out = D^{-1/2} A D^{-1/2} x
// x: f32 [N, 64]; edge_index: int32 on device (harness downcasts int64), [2, E]
//
// Pipeline:
//  K1 bin_kernel: per 8192-edge tile, LDS count/scan/reorder by dst-bin,
//     sequential flush of packed 4B records ((dloc<<23)|src) + directory.
//  K3 csr_build: one block per bin; records in LDS once; histogram -> dis +
//     row_ptr; then BUCKET-ORDERED scatter (src>>13 passes) so each CSR row
//     is sorted by src high bits -> phase-aligned xs sweep in gather.
//  K4 stage_xs: xs[s] = dis[s]*x[s] fp16, overlaid on dead records region.
//  K5 gather_s: 4 nodes/wave, 16 lanes/node (8B col each); serial edge walk
//     (unroll 2), register accumulation, no shfl, float4 store. Sorted rows +
//     serial walk keep the concurrent cohort's src window ~1-2MB (L2-fit).

#define DFEAT 64
#define BIN_W 391          // nodes per bin; NB = ceil(N/BIN_W) must be <= 256
#define TILE 8192          // edges per K1 block
#define K1_THREADS 256
#define EPT (TILE / K1_THREADS)   // 32
#define DIRW 257
#define K3_THREADS 1024
#define MAX_NT 512         // run-bound cache capacity; NT must be <= this
#define CAP 8192           // LDS record capacity (mean 6250, +24 sigma)

typedef unsigned long long u64;
typedef unsigned int u32;
typedef float f4v __attribute__((ext_vector_type(4)));

// ---------------- K1: LDS-reordered binning, packed 4B records ----------------
__global__ __launch_bounds__(K1_THREADS)
void bin_kernel(const int* __restrict__ src, const int* __restrict__ dst,
                u32* __restrict__ records, int* __restrict__ dir,
                int* __restrict__ bin_cnt, int E, int N) {
    __shared__ int cnt[256];
    __shared__ int off[DIRW];
    __shared__ int rnk[256];
    __shared__ u32 buf[TILE];

    const int t    = blockIdx.x;
    const int base = t * TILE;
    const int tid  = threadIdx.x;

    cnt[tid] = 0;
    rnk[tid] = 0;
    __syncthreads();

    u32 rec[EPT];
    int myb[EPT];
    #pragma unroll
    for (int i = 0; i < EPT; ++i) {
        int e = base + tid + i * K1_THREADS;
        int b = -1;
        u32 r = 0;
        if (e < E) {
            unsigned d = (unsigned)dst[e];
            unsigned s = (unsigned)src[e];
            if (d < (unsigned)N && s < (unsigned)N) {
                b = (int)(d / BIN_W);
                r = ((d - (unsigned)b * BIN_W) << 23) | s;   // dloc<9b> | src<23b>
            }
        }
        myb[i] = b;
        rec[i] = r;
        if (b >= 0) atomicAdd(&cnt[b], 1);
    }
    __syncthreads();

    int v = cnt[tid];
    off[tid] = v;
    __syncthreads();
    for (int d = 1; d < 256; d <<= 1) {
        int add = (tid >= d) ? off[tid - d] : 0;
        __syncthreads();
        off[tid] += add;
        __syncthreads();
    }
    int incl = off[tid];
    __syncthreads();
    off[tid] = incl - v;
    if (tid == 255) off[256] = incl;
    __syncthreads();

    dir[t * DIRW + tid] = off[tid];
    if (tid == 0) dir[t * DIRW + 256] = off[256];
    if (v > 0) atomicAdd(&bin_cnt[tid], v);

    #pragma unroll
    for (int i = 0; i < EPT; ++i) {
        int b = myb[i];
        if (b >= 0) {
            int r = atomicAdd(&rnk[b], 1);
            buf[off[b] + r] = rec[i];
        }
    }
    __syncthreads();

    int total = off[256];
    for (int i = tid; i < total; i += K1_THREADS)
        records[(size_t)base + i] = buf[i];
}

// ---------------- K3: per-bin CSR build + src-bucket-ordered scatter ----------------
__global__ __launch_bounds__(K3_THREADS)
void csr_build_kernel(const u32* __restrict__ records,
                      const int* __restrict__ dir,
                      const int* __restrict__ bin_cnt,
                      float* __restrict__ dis,
                      int* __restrict__ row_ptr,
                      int* __restrict__ csr_src, int N, int NT, int NB,
                      int bshift, int nbuckets) {
    __shared__ u32 ldsrec[CAP];     // 32KB
    __shared__ int deg[512];        // scratch: bin-scan, len-scan, histogram
    __shared__ int cur[BIN_W];
    __shared__ int sbeg[MAX_NT];
    __shared__ int send[MAX_NT];
    __shared__ int lofs[MAX_NT];
    __shared__ int sh_total, sh_gb0;

    const int b  = blockIdx.x;
    const int lo = b * BIN_W;
    const int nodes = min(BIN_W, N - lo);
    const int tid = threadIdx.x;
    const int wave = tid >> 6, lane = tid & 63;

    // --- fused bin_base scan ---
    int bv = 0;
    if (tid < 512) { bv = (tid < NB) ? bin_cnt[tid] : 0; deg[tid] = bv; }
    __syncthreads();
    for (int d = 1; d < 512; d <<= 1) {
        int a = (tid < 512 && tid >= d) ? deg[tid - d] : 0;
        __syncthreads();
        if (tid < 512) deg[tid] += a;
        __syncthreads();
    }
    if (tid == b) sh_gb0 = deg[tid] - bv;
    if (b == 0 && tid == 0) row_ptr[N] = deg[NB - 1];
    __syncthreads();

    // --- run bounds + LDS-offset scan ---
    for (int t = tid; t < NT; t += K3_THREADS) {
        sbeg[t] = dir[t * DIRW + b];
        send[t] = dir[t * DIRW + b + 1];
    }
    __syncthreads();
    if (tid < 512) deg[tid] = (tid < NT) ? (send[tid] - sbeg[tid]) : 0;
    __syncthreads();
    for (int d = 1; d < 512; d <<= 1) {
        int a = (tid < 512 && tid >= d) ? deg[tid - d] : 0;
        __syncthreads();
        if (tid < 512) deg[tid] += a;
        __syncthreads();
    }
    if (tid < NT) lofs[tid] = deg[tid] - (send[tid] - sbeg[tid]);
    if (tid == 0) sh_total = deg[511];
    __syncthreads();

    const int total = sh_total;
    const bool fits = (total <= CAP);

    // --- copy records into LDS: 2 runs per wave (32 lanes each) ---
    if (fits) {
        for (int rb = wave * 2; rb < NT; rb += 32) {
            int r = rb + (lane >> 5);
            if (r < NT) {
                int g0  = r * TILE + sbeg[r];
                int l0  = lofs[r];
                int len = send[r] - sbeg[r];
                for (int k = (lane & 31); k < len; k += 32)
                    ldsrec[l0 + k] = records[g0 + k];
            }
        }
    }
    __syncthreads();

    // --- histogram ---
    if (tid < 512) deg[tid] = 0;
    __syncthreads();
    if (fits) {
        for (int i = tid; i < total; i += K3_THREADS)
            atomicAdd(&deg[ldsrec[i] >> 23], 1);
    } else {
        for (int t = wave; t < NT; t += 16) {
            int s = sbeg[t], e = send[t], gb = t * TILE;
            for (int k = s + lane; k < e; k += 64)
                atomicAdd(&deg[records[gb + k] >> 23], 1);
        }
    }
    __syncthreads();

    // --- dis slice ---
    if (tid < nodes) {
        int c = deg[tid];
        dis[lo + tid] = (c > 0) ? rsqrtf((float)c) : 0.0f;
    }

    // --- scan degrees -> row_ptr + cursors ---
    int v0 = (tid < 512) ? deg[tid] : 0;
    __syncthreads();
    for (int d = 1; d < 512; d <<= 1) {
        int a = (tid < 512 && tid >= d) ? deg[tid - d] : 0;
        __syncthreads();
        if (tid < 512) deg[tid] += a;
        __syncthreads();
    }
    if (tid < nodes) {
        int g = sh_gb0 + deg[tid] - v0;
        row_ptr[lo + tid] = g;
        cur[tid] = g;
    }
    __syncthreads();

    // --- scatter src, bucket-ordered by src>>bshift (rows sorted coarsely) ---
    if (fits) {
        for (int p = 0; p < nbuckets; ++p) {
            for (int i = tid; i < total; i += K3_THREADS) {
                u32 r = ldsrec[i];
                u32 s = r & 0x7FFFFF;
                if ((int)(s >> bshift) == p) {
                    int pos = atomicAdd(&cur[r >> 23], 1);
                    csr_src[pos] = (int)s;
                }
            }
            __syncthreads();
        }
    } else {
        for (int t = wave; t < NT; t += 16) {
            int s = sbeg[t], e = send[t], gb = t * TILE;
            for (int k = s + lane; k < e; k += 64) {
                u32 r = records[gb + k];
                int p = atomicAdd(&cur[r >> 23], 1);
                csr_src[p] = (int)(r & 0x7FFFFF);
            }
        }
    }
}

// ---------------- K4: stage xs = dis[s] * x[s] -> fp16 (__half2 pairs) ----------------
__global__ __launch_bounds__(256)
void stage_xs_kernel(const float* __restrict__ x, const float* __restrict__ dis,
                     __half2* __restrict__ xs, int total4 /* N*DFEAT/4 */) {
    int i = blockIdx.x * blockDim.x + threadIdx.x;
    if (i < total4) {
        float w = dis[i >> 4];   // 16 float4 per node
        float4 f = *reinterpret_cast<const float4*>(x + (size_t)i * 4);
        xs[i * 2]     = __floats2half2_rn(f.x * w, f.y * w);
        xs[i * 2 + 1] = __floats2half2_rn(f.z * w, f.w * w);
    }
}

// ---------------- K5: gather — 4 nodes/wave, serial src-sorted walk ----------------
// lane = q*16 + c8: q = node-of-quad (0..3), c8 = 8B column (features 4c8..4c8+3)
struct alignas(8) h4 { __half2 a, b; };

__global__ void gather_s_kernel(const h4* __restrict__ xs4,
                                const int* __restrict__ row_ptr,
                                const int* __restrict__ csr_src,
                                const float* __restrict__ dis,
                                float* __restrict__ out, int N) {
    long long gt = blockIdx.x * (long long)blockDim.x + threadIdx.x;
    int node = (int)((gt >> 6) * 4) + ((threadIdx.x & 63) >> 4);
    int c8 = threadIdx.x & 15;
    if (node >= N) return;
    int beg = row_ptr[node];
    int end = row_ptr[node + 1];
    float a0 = 0.0f, a1 = 0.0f, a2 = 0.0f, a3 = 0.0f;
    int k = beg;
    for (; k + 1 < end; k += 2) {          // serial walk, 2 edges in flight
        int s0 = csr_src[k];
        int s1 = csr_src[k + 1];
        h4 v0 = xs4[(size_t)s0 * 16 + c8];
        h4 v1 = xs4[(size_t)s1 * 16 + c8];
        float2 f00 = __half22float2(v0.a), f01 = __half22float2(v0.b);
        float2 f10 = __half22float2(v1.a), f11 = __half22float2(v1.b);
        a0 += f00.x + f10.x;
        a1 += f00.y + f10.y;
        a2 += f01.x + f11.x;
        a3 += f01.y + f11.y;
    }
    if (k < end) {
        int s0 = csr_src[k];
        h4 v0 = xs4[(size_t)s0 * 16 + c8];
        float2 f00 = __half22float2(v0.a), f01 = __half22float2(v0.b);
        a0 += f00.x; a1 += f00.y; a2 += f01.x; a3 += f01.y;
    }
    float dd = dis[node];
    f4v o = { a0 * dd, a1 * dd, a2 * dd, a3 * dd };
    __builtin_nontemporal_store(o, (f4v*)(out + (size_t)node * DFEAT + c8 * 4));
}

// ---------------- fallback (atomic scatter) if ws too small ----------------
__global__ void fb_deg_kernel(const int* __restrict__ dst,
                              float* __restrict__ deg, int E, int N) {
    int e = blockIdx.x * blockDim.x + threadIdx.x;
    if (e < E) {
        unsigned d = (unsigned)dst[e];
        if (d < (unsigned)N) unsafeAtomicAdd(&deg[d], 1.0f);
    }
}
__global__ void fb_dis_kernel(float* __restrict__ deg, int N) {
    int i = blockIdx.x * blockDim.x + threadIdx.x;
    if (i < N) {
        float d = deg[i];
        deg[i] = (d > 0.0f) ? rsqrtf(d) : 0.0f;
    }
}
__global__ void fb_scatter_kernel(const float* __restrict__ x,
                                  const int* __restrict__ src,
                                  const int* __restrict__ dst,
                                  const float* __restrict__ dis,
                                  float* __restrict__ out, int E, int N) {
    long long t = (long long)blockIdx.x * blockDim.x + threadIdx.x;
    int e = (int)(t >> 4);
    int c = (int)(t & 15);
    if (e >= E) return;
    unsigned s = (unsigned)src[e];
    unsigned d = (unsigned)dst[e];
    if (s >= (unsigned)N || d >= (unsigned)N) return;
    float norm = dis[s] * dis[d];
    const float4 v = *reinterpret_cast<const float4*>(x + (size_t)s * DFEAT + c * 4);
    float* o = out + (size_t)d * DFEAT + c * 4;
    unsafeAtomicAdd(o + 0, v.x * norm);
    unsafeAtomicAdd(o + 1, v.y * norm);
    unsafeAtomicAdd(o + 2, v.z * norm);
    unsafeAtomicAdd(o + 3, v.w * norm);
}

extern "C" void kernel_launch(void* const* d_in, const int* in_sizes, int n_in,
                              void* d_out, int out_size, void* d_ws, size_t ws_size,
                              hipStream_t stream) {
    const float* x  = (const float*)d_in[0];
    const int*   ei = (const int*)d_in[1];   // harness delivers integer inputs as int32

    const int N = in_sizes[0] / DFEAT;        // 100000
    const int E = in_sizes[1] / 2;            // 1600000
    const int* src = ei;                      // row 0
    const int* dst = ei + E;                  // row 1

    float* out = (float*)d_out;

    const int NB = (N + BIN_W - 1) / BIN_W;   // bins (256 for N=100000)
    const int NT = (E + TILE - 1) / TILE;     // tiles (196 for E=1.6M)

    // src bucket shift: ~16 buckets over [0,N)
    int bshift = 13;
    while ((((N - 1) >> bshift) + 1) > 16) bshift++;
    int nbuckets = ((N - 1) >> bshift) + 1;

    // workspace layout (16B-aligned chunks)
    char* base = (char*)d_ws;
    size_t off = 0;
    auto alloc = [&](size_t bytes) { void* p = base + off; off += (bytes + 15) & ~(size_t)15; return p; };
    size_t rec_bytes = (size_t)NT * TILE * 4;
    size_t xs_bytes  = (size_t)N * DFEAT * 2;
    size_t region    = rec_bytes > xs_bytes ? rec_bytes : xs_bytes;
    u32*   records  = (u32*)alloc(region);    // records, later overlaid by xs
    int*   dir      = (int*)alloc((size_t)NT * DIRW * 4);
    int*   bin_cnt  = (int*)alloc(256 * 4);
    float* dis      = (float*)alloc((size_t)N * 4);
    int*   row_ptr  = (int*)alloc((size_t)(N + 1) * 4);
    int*   csr_src  = (int*)alloc((size_t)E * 4);

    const bool ok = (off <= ws_size) && (NB <= 256) && (NT <= MAX_NT) &&
                    (N <= (1 << 23)) && (BIN_W <= 512);

    if (ok) {
        hipMemsetAsync(bin_cnt, 0, 256 * 4, stream);

        bin_kernel<<<NT, K1_THREADS, 0, stream>>>(src, dst, records, dir, bin_cnt, E, N);
        csr_build_kernel<<<NB, K3_THREADS, 0, stream>>>(records, dir, bin_cnt, dis,
                                                        row_ptr, csr_src, N, NT, NB,
                                                        bshift, nbuckets);

        __half2* xs = (__half2*)records;      // overlay: records dead after K3
        int total4 = N * DFEAT / 4;
        stage_xs_kernel<<<(total4 + 255) / 256, 256, 0, stream>>>(x, dis, xs, total4);

        // 16 nodes per 256-thread block (4 nodes per wave)
        int gblocks = (N + 15) / 16;
        gather_s_kernel<<<gblocks, 256, 0, stream>>>((const h4*)xs, row_ptr, csr_src, dis, out, N);
    } else {
        // fallback: atomic scatter (needs only N floats of ws)
        float* deg = (float*)d_ws;
        hipMemsetAsync(deg, 0, (size_t)N * 4, stream);
        hipMemsetAsync(out, 0, (size_t)out_size * 4, stream);
        int eb = (E + 255) / 256;
        fb_deg_kernel<<<eb, 256, 0, stream>>>(dst, deg, E, N);
        int nb = (N + 255) / 256;
        fb_dis_kernel<<<nb, 256, 0, stream>>>(deg, N);
        long long total = (long long)E * 16;
        int sb = (int)((total + 255) / 256);
        fb_scatter_kernel<<<sb, 256, 0, stream>>>(x, src, dst, deg, out, E, N);
    }
}

// Round 15
// 97.264 us; speedup vs baseline: 6.8718x; 1.0981x over previous
//
#include <hip/hip_runtime.h>
#include <hip/hip_fp16.h>

// LGConv: out = D^{-1/2} A D^{-1/2} x
// x: f32 [N, 64]; edge_index: int32 on device (harness downcasts int64), [2, E]
//
// Pipeline:
//  K1 bin_kernel: per 8192-edge tile, LDS count/scan/reorder by dst-bin,
//     sequential flush of packed 4B records ((dloc<<23)|src) + directory.
//  K3 csr_build: one block per bin; records in LDS once; single-pass
//     (node,bucket)-keyed counting sort: histogram cnt2[dloc*16+bucket] ->
//     dis + ownership scan -> cursors -> one scatter pass. Rows come out
//     bucket-sorted by src (ascending high bits) for the phase-local gather.
//  K4 stage_xs: xs[s] = dis[s]*x[s] fp16, overlaid on dead records region.
//  K5 gather_s: 4 nodes/wave, 16 lanes/node (8B col each); serial sorted
//     walk, unroll 4 (4 lines in flight), nontemporal csr, float4 store.

#define DFEAT 64
#define BIN_W 391          // nodes per bin; NB = ceil(N/BIN_W) must be <= 256
#define TILE 8192          // edges per K1 block
#define K1_THREADS 256
#define EPT (TILE / K1_THREADS)   // 32
#define DIRW 257
#define K3_THREADS 1024
#define MAX_NT 512         // NT must be <= this (and <= K3_THREADS)
#define CAP 8192           // LDS record capacity (mean 6250, +24 sigma)
#define NBUCK 16
#define KMAXP (BIN_W * NBUCK)            // 6256 keys
#define KPT ((KMAXP + K3_THREADS - 1) / K3_THREADS)  // 7 keys per thread

typedef unsigned long long u64;
typedef unsigned int u32;
typedef float f4v __attribute__((ext_vector_type(4)));

// ---------------- K1: LDS-reordered binning, packed 4B records ----------------
__global__ __launch_bounds__(K1_THREADS)
void bin_kernel(const int* __restrict__ src, const int* __restrict__ dst,
                u32* __restrict__ records, int* __restrict__ dir,
                int* __restrict__ bin_cnt, int E, int N) {
    __shared__ int cnt[256];
    __shared__ int off[DIRW];
    __shared__ int rnk[256];
    __shared__ u32 buf[TILE];

    const int t    = blockIdx.x;
    const int base = t * TILE;
    const int tid  = threadIdx.x;

    cnt[tid] = 0;
    rnk[tid] = 0;
    __syncthreads();

    u32 rec[EPT];
    int myb[EPT];
    #pragma unroll
    for (int i = 0; i < EPT; ++i) {
        int e = base + tid + i * K1_THREADS;
        int b = -1;
        u32 r = 0;
        if (e < E) {
            unsigned d = (unsigned)dst[e];
            unsigned s = (unsigned)src[e];
            if (d < (unsigned)N && s < (unsigned)N) {
                b = (int)(d / BIN_W);
                r = ((d - (unsigned)b * BIN_W) << 23) | s;   // dloc<9b> | src<23b>
            }
        }
        myb[i] = b;
        rec[i] = r;
        if (b >= 0) atomicAdd(&cnt[b], 1);
    }
    __syncthreads();

    int v = cnt[tid];
    off[tid] = v;
    __syncthreads();
    for (int d = 1; d < 256; d <<= 1) {
        int add = (tid >= d) ? off[tid - d] : 0;
        __syncthreads();
        off[tid] += add;
        __syncthreads();
    }
    int incl = off[tid];
    __syncthreads();
    off[tid] = incl - v;
    if (tid == 255) off[256] = incl;
    __syncthreads();

    dir[t * DIRW + tid] = off[tid];
    if (tid == 0) dir[t * DIRW + 256] = off[256];
    if (v > 0) atomicAdd(&bin_cnt[tid], v);

    #pragma unroll
    for (int i = 0; i < EPT; ++i) {
        int b = myb[i];
        if (b >= 0) {
            int r = atomicAdd(&rnk[b], 1);
            buf[off[b] + r] = rec[i];
        }
    }
    __syncthreads();

    int total = off[256];
    for (int i = tid; i < total; i += K1_THREADS)
        records[(size_t)base + i] = buf[i];
}

// ---------------- K3: per-bin CSR build, one-pass keyed counting sort ----------------
__global__ __launch_bounds__(K3_THREADS)
void csr_build_kernel(const u32* __restrict__ records,
                      const int* __restrict__ dir,
                      const int* __restrict__ bin_cnt,
                      float* __restrict__ dis,
                      int* __restrict__ row_ptr,
                      int* __restrict__ csr_src, int N, int NT, int NB,
                      int bshift) {
    __shared__ u32 ldsrec[CAP];       // 32KB
    __shared__ int cnt2[KMAXP];       // 25KB: histogram, then cursors
    __shared__ int psum[K3_THREADS];  // 4KB scan scratch
    __shared__ int sbeg[MAX_NT];
    __shared__ int send[MAX_NT];
    __shared__ int lofs[MAX_NT];
    __shared__ int sh_total, sh_gb0;

    const int b  = blockIdx.x;
    const int lo = b * BIN_W;
    const int nodes = min(BIN_W, N - lo);
    const int tid = threadIdx.x;
    const int wave = tid >> 6, lane = tid & 63;

    // --- bin_base scan (psum scratch) ---
    int bv = (tid < NB) ? bin_cnt[tid] : 0;
    psum[tid] = bv;
    __syncthreads();
    for (int d = 1; d < K3_THREADS; d <<= 1) {
        int a = (tid >= d) ? psum[tid - d] : 0;
        __syncthreads();
        psum[tid] += a;
        __syncthreads();
    }
    if (tid == b) sh_gb0 = psum[tid] - bv;
    if (b == 0 && tid == NB - 1) row_ptr[N] = psum[tid];
    __syncthreads();

    // --- run bounds + LDS-offset scan (NT <= K3_THREADS) ---
    int len = 0;
    if (tid < NT) {
        sbeg[tid] = dir[tid * DIRW + b];
        send[tid] = dir[tid * DIRW + b + 1];
        len = send[tid] - sbeg[tid];
    }
    psum[tid] = len;
    __syncthreads();
    for (int d = 1; d < K3_THREADS; d <<= 1) {
        int a = (tid >= d) ? psum[tid - d] : 0;
        __syncthreads();
        psum[tid] += a;
        __syncthreads();
    }
    if (tid < NT) lofs[tid] = psum[tid] - len;
    if (tid == K3_THREADS - 1) sh_total = psum[tid];
    __syncthreads();

    const int total = sh_total;
    const bool fits = (total <= CAP);

    // --- copy records into LDS: 2 runs per wave (32 lanes each) ---
    if (fits) {
        for (int rb = wave * 2; rb < NT; rb += 32) {
            int r = rb + (lane >> 5);
            if (r < NT) {
                int g0  = r * TILE + sbeg[r];
                int l0  = lofs[r];
                int ln  = send[r] - sbeg[r];
                for (int k = (lane & 31); k < ln; k += 32)
                    ldsrec[l0 + k] = records[g0 + k];
            }
        }
    }
    __syncthreads();

    // --- keyed histogram: key = dloc*16 + (src>>bshift) ---
    for (int i = tid; i < KMAXP; i += K3_THREADS) cnt2[i] = 0;
    __syncthreads();
    if (fits) {
        for (int i = tid; i < total; i += K3_THREADS) {
            u32 r = ldsrec[i];
            int key = (int)(r >> 23) * NBUCK + (int)((r & 0x7FFFFF) >> bshift);
            atomicAdd(&cnt2[key], 1);
        }
    } else {
        for (int t = wave; t < NT; t += 16) {
            int s = sbeg[t], e = send[t], gb = t * TILE;
            for (int k = s + lane; k < e; k += 64) {
                u32 r = records[gb + k];
                int key = (int)(r >> 23) * NBUCK + (int)((r & 0x7FFFFF) >> bshift);
                atomicAdd(&cnt2[key], 1);
            }
        }
    }
    __syncthreads();

    // --- dis from per-node bucket sums ---
    if (tid < nodes) {
        int c = 0;
        #pragma unroll
        for (int j = 0; j < NBUCK; ++j) c += cnt2[tid * NBUCK + j];
        dis[lo + tid] = (c > 0) ? rsqrtf((float)c) : 0.0f;
    }

    // --- ownership scan over KMAXP keys (KPT per thread) ---
    int base7 = tid * KPT;
    int loc[KPT];
    int s = 0;
    #pragma unroll
    for (int j = 0; j < KPT; ++j) {
        int k = base7 + j;
        loc[j] = s;
        if (k < KMAXP) s += cnt2[k];
    }
    psum[tid] = s;
    __syncthreads();
    for (int d = 1; d < K3_THREADS; d <<= 1) {
        int a = (tid >= d) ? psum[tid - d] : 0;
        __syncthreads();
        psum[tid] += a;
        __syncthreads();
    }
    int excl = psum[tid] - s;
    __syncthreads();
    // cursors (global positions); each thread writes only its own keys
    #pragma unroll
    for (int j = 0; j < KPT; ++j) {
        int k = base7 + j;
        if (k < KMAXP) cnt2[k] = sh_gb0 + excl + loc[j];
    }
    __syncthreads();

    // --- row_ptr = cursor of each node's bucket 0 (before scatter mutates) ---
    if (tid < nodes) row_ptr[lo + tid] = cnt2[tid * NBUCK];
    __syncthreads();

    // --- single scatter pass (bucket-sorted rows via key order) ---
    if (fits) {
        for (int i = tid; i < total; i += K3_THREADS) {
            u32 r = ldsrec[i];
            u32 sc = r & 0x7FFFFF;
            int key = (int)(r >> 23) * NBUCK + (int)(sc >> bshift);
            int pos = atomicAdd(&cnt2[key], 1);
            csr_src[pos] = (int)sc;
        }
    } else {
        for (int t = wave; t < NT; t += 16) {
            int s0 = sbeg[t], e0 = send[t], gb = t * TILE;
            for (int k = s0 + lane; k < e0; k += 64) {
                u32 r = records[gb + k];
                u32 sc = r & 0x7FFFFF;
                int key = (int)(r >> 23) * NBUCK + (int)(sc >> bshift);
                int pos = atomicAdd(&cnt2[key], 1);
                csr_src[pos] = (int)sc;
            }
        }
    }
}

// ---------------- K4: stage xs = dis[s] * x[s] -> fp16 (__half2 pairs) ----------------
__global__ __launch_bounds__(256)
void stage_xs_kernel(const float* __restrict__ x, const float* __restrict__ dis,
                     __half2* __restrict__ xs, int total4 /* N*DFEAT/4 */) {
    int i = blockIdx.x * blockDim.x + threadIdx.x;
    if (i < total4) {
        float w = dis[i >> 4];   // 16 float4 per node
        float4 f = *reinterpret_cast<const float4*>(x + (size_t)i * 4);
        xs[i * 2]     = __floats2half2_rn(f.x * w, f.y * w);
        xs[i * 2 + 1] = __floats2half2_rn(f.z * w, f.w * w);
    }
}

// ---------------- K5: gather — 4 nodes/wave, serial src-sorted walk, unroll 4 ----------------
// lane = q*16 + c8: q = node-of-quad (0..3), c8 = 8B column (features 4c8..4c8+3)
struct alignas(8) h4 { __half2 a, b; };

__global__ void gather_s_kernel(const h4* __restrict__ xs4,
                                const int* __restrict__ row_ptr,
                                const int* __restrict__ csr_src,
                                const float* __restrict__ dis,
                                float* __restrict__ out, int N) {
    long long gt = blockIdx.x * (long long)blockDim.x + threadIdx.x;
    int node = (int)((gt >> 6) * 4) + ((threadIdx.x & 63) >> 4);
    int c8 = threadIdx.x & 15;
    if (node >= N) return;
    int beg = row_ptr[node];
    int end = row_ptr[node + 1];
    float a0 = 0.0f, a1 = 0.0f, a2 = 0.0f, a3 = 0.0f;
    int k = beg;
    for (; k + 3 < end; k += 4) {          // serial sorted walk, 4 lines in flight
        int s0 = __builtin_nontemporal_load(csr_src + k);
        int s1 = __builtin_nontemporal_load(csr_src + k + 1);
        int s2 = __builtin_nontemporal_load(csr_src + k + 2);
        int s3 = __builtin_nontemporal_load(csr_src + k + 3);
        h4 v0 = xs4[(size_t)s0 * 16 + c8];
        h4 v1 = xs4[(size_t)s1 * 16 + c8];
        h4 v2 = xs4[(size_t)s2 * 16 + c8];
        h4 v3 = xs4[(size_t)s3 * 16 + c8];
        float2 f00 = __half22float2(v0.a), f01 = __half22float2(v0.b);
        float2 f10 = __half22float2(v1.a), f11 = __half22float2(v1.b);
        float2 f20 = __half22float2(v2.a), f21 = __half22float2(v2.b);
        float2 f30 = __half22float2(v3.a), f31 = __half22float2(v3.b);
        a0 += (f00.x + f10.x) + (f20.x + f30.x);
        a1 += (f00.y + f10.y) + (f20.y + f30.y);
        a2 += (f01.x + f11.x) + (f21.x + f31.x);
        a3 += (f01.y + f11.y) + (f21.y + f31.y);
    }
    for (; k < end; ++k) {
        int s0 = __builtin_nontemporal_load(csr_src + k);
        h4 v0 = xs4[(size_t)s0 * 16 + c8];
        float2 f00 = __half22float2(v0.a), f01 = __half22float2(v0.b);
        a0 += f00.x; a1 += f00.y; a2 += f01.x; a3 += f01.y;
    }
    float dd = dis[node];
    f4v o = { a0 * dd, a1 * dd, a2 * dd, a3 * dd };
    __builtin_nontemporal_store(o, (f4v*)(out + (size_t)node * DFEAT + c8 * 4));
}

// ---------------- fallback (atomic scatter) if ws too small ----------------
__global__ void fb_deg_kernel(const int* __restrict__ dst,
                              float* __restrict__ deg, int E, int N) {
    int e = blockIdx.x * blockDim.x + threadIdx.x;
    if (e < E) {
        unsigned d = (unsigned)dst[e];
        if (d < (unsigned)N) unsafeAtomicAdd(&deg[d], 1.0f);
    }
}
__global__ void fb_dis_kernel(float* __restrict__ deg, int N) {
    int i = blockIdx.x * blockDim.x + threadIdx.x;
    if (i < N) {
        float d = deg[i];
        deg[i] = (d > 0.0f) ? rsqrtf(d) : 0.0f;
    }
}
__global__ void fb_scatter_kernel(const float* __restrict__ x,
                                  const int* __restrict__ src,
                                  const int* __restrict__ dst,
                                  const float* __restrict__ dis,
                                  float* __restrict__ out, int E, int N) {
    long long t = (long long)blockIdx.x * blockDim.x + threadIdx.x;
    int e = (int)(t >> 4);
    int c = (int)(t & 15);
    if (e >= E) return;
    unsigned s = (unsigned)src[e];
    unsigned d = (unsigned)dst[e];
    if (s >= (unsigned)N || d >= (unsigned)N) return;
    float norm = dis[s] * dis[d];
    const float4 v = *reinterpret_cast<const float4*>(x + (size_t)s * DFEAT + c * 4);
    float* o = out + (size_t)d * DFEAT + c * 4;
    unsafeAtomicAdd(o + 0, v.x * norm);
    unsafeAtomicAdd(o + 1, v.y * norm);
    unsafeAtomicAdd(o + 2, v.z * norm);
    unsafeAtomicAdd(o + 3, v.w * norm);
}

extern "C" void kernel_launch(void* const* d_in, const int* in_sizes, int n_in,
                              void* d_out, int out_size, void* d_ws, size_t ws_size,
                              hipStream_t stream) {
    const float* x  = (const float*)d_in[0];
    const int*   ei = (const int*)d_in[1];   // harness delivers integer inputs as int32

    const int N = in_sizes[0] / DFEAT;        // 100000
    const int E = in_sizes[1] / 2;            // 1600000
    const int* src = ei;                      // row 0
    const int* dst = ei + E;                  // row 1

    float* out = (float*)d_out;

    const int NB = (N + BIN_W - 1) / BIN_W;   // bins (256 for N=100000)
    const int NT = (E + TILE - 1) / TILE;     // tiles (196 for E=1.6M)

    // src bucket shift: <= NBUCK buckets over [0,N)
    int bshift = 13;
    while ((((N - 1) >> bshift) + 1) > NBUCK) bshift++;

    // workspace layout (16B-aligned chunks)
    char* base = (char*)d_ws;
    size_t off = 0;
    auto alloc = [&](size_t bytes) { void* p = base + off; off += (bytes + 15) & ~(size_t)15; return p; };
    size_t rec_bytes = (size_t)NT * TILE * 4;
    size_t xs_bytes  = (size_t)N * DFEAT * 2;
    size_t region    = rec_bytes > xs_bytes ? rec_bytes : xs_bytes;
    u32*   records  = (u32*)alloc(region);    // records, later overlaid by xs
    int*   dir      = (int*)alloc((size_t)NT * DIRW * 4);
    int*   bin_cnt  = (int*)alloc(256 * 4);
    float* dis      = (float*)alloc((size_t)N * 4);
    int*   row_ptr  = (int*)alloc((size_t)(N + 1) * 4);
    int*   csr_src  = (int*)alloc((size_t)E * 4);

    const bool ok = (off <= ws_size) && (NB <= 256) && (NT <= MAX_NT) &&
                    (NT <= K3_THREADS) && (N <= (1 << 23)) && (BIN_W <= 512);

    if (ok) {
        hipMemsetAsync(bin_cnt, 0, 256 * 4, stream);

        bin_kernel<<<NT, K1_THREADS, 0, stream>>>(src, dst, records, dir, bin_cnt, E, N);
        csr_build_kernel<<<NB, K3_THREADS, 0, stream>>>(records, dir, bin_cnt, dis,
                                                        row_ptr, csr_src, N, NT, NB,
                                                        bshift);

        __half2* xs = (__half2*)records;      // overlay: records dead after K3
        int total4 = N * DFEAT / 4;
        stage_xs_kernel<<<(total4 + 255) / 256, 256, 0, stream>>>(x, dis, xs, total4);

        // 16 nodes per 256-thread block (4 nodes per wave)
        int gblocks = (N + 15) / 16;
        gather_s_kernel<<<gblocks, 256, 0, stream>>>((const h4*)xs, row_ptr, csr_src, dis, out, N);
    } else {
        // fallback: atomic scatter (needs only N floats of ws)
        float* deg = (float*)d_ws;
        hipMemsetAsync(deg, 0, (size_t)N * 4, stream);
        hipMemsetAsync(out, 0, (size_t)out_size * 4, stream);
        int eb = (E + 255) / 256;
        fb_deg_kernel<<<eb, 256, 0, stream>>>(dst, deg, E, N);
        int nb = (N + 255) / 256;
        fb_dis_kernel<<<nb, 256, 0, stream>>>(deg, N);
        long long total = (long long)E * 16;
        int sb = (int)((total + 255) / 256);
        fb_scatter_kernel<<<sb, 256, 0, stream>>>(x, src, dst, deg, out, E, N);
    }
}

// Round 16
// 86.457 us; speedup vs baseline: 7.7308x; 1.1250x over previous
//
#include <hip/hip_runtime.h>
#include <hip/hip_fp16.h>

// LGConv: out = D^{-1/2} A D^{-1/2} x
// x: f32 [N, 64]; edge_index: int32 on device (harness downcasts int64), [2, E]
//
// Pipeline:
//  K1 bin_kernel: per 8192-edge tile, LDS count(+rank)/scan/reorder by
//     dst-bin, sequential flush of packed 4B records ((dloc<<23)|src) +
//     directory. int4 edge loads, single LDS atomic per edge, wave-scan.
//  K3 csr_build: one block per bin; records in LDS once; single-pass
//     (node,bucket)-keyed counting sort -> dis, row_ptr, bucket-sorted rows.
//     All scans are shfl_up wave-scans (2 barriers each).
//  K4 stage_xs: xs[s] = dis[s]*x[s] fp16, overlaid on dead records region.
//  K5 gather_s: 4 nodes/wave, 16 lanes/node (8B col each); serial sorted
//     walk, unroll 8 (8 lines in flight), nontemporal csr, float4 store.

#define DFEAT 64
#define BIN_W 391          // nodes per bin; NB = ceil(N/BIN_W) must be <= 256
#define TILE 8192          // edges per K1 block
#define K1_THREADS 256
#define EPT (TILE / K1_THREADS)   // 32
#define DIRW 257
#define K3_THREADS 1024
#define MAX_NT 512         // NT must be <= this (and <= K3_THREADS)
#define CAP 8192           // LDS record capacity (mean 6250, +24 sigma)
#define NBUCK 16
#define KMAXP (BIN_W * NBUCK)            // 6256 keys
#define KPT ((KMAXP + K3_THREADS - 1) / K3_THREADS)  // 7 keys per thread

typedef unsigned long long u64;
typedef unsigned int u32;
typedef float f4v __attribute__((ext_vector_type(4)));

// ---------------- K1: LDS-reordered binning, packed 4B records ----------------
__global__ __launch_bounds__(K1_THREADS)
void bin_kernel(const int* __restrict__ src, const int* __restrict__ dst,
                u32* __restrict__ records, int* __restrict__ dir,
                int* __restrict__ bin_cnt, int E, int N) {
    __shared__ int cnt[256];
    __shared__ int off[DIRW];
    __shared__ int wsum[5];
    __shared__ u32 buf[TILE];

    const int t    = blockIdx.x;
    const int base = t * TILE;
    const int tid  = threadIdx.x;
    const int lane = tid & 63, wave = tid >> 6;

    cnt[tid] = 0;
    __syncthreads();

    // phase A: vectorized load + count-with-rank (one LDS atomic per edge)
    u32 rec[EPT];
    int mybr[EPT];                  // (bin<<16)|rank, or -1
    #pragma unroll
    for (int j = 0; j < EPT / 4; ++j) {
        int e0 = base + 4 * (tid + j * K1_THREADS);
        int4 s4, d4;
        if (e0 + 3 < E) {
            s4 = *reinterpret_cast<const int4*>(src + e0);
            d4 = *reinterpret_cast<const int4*>(dst + e0);
        } else {
            s4.x = (e0 + 0 < E) ? src[e0 + 0] : -1;
            s4.y = (e0 + 1 < E) ? src[e0 + 1] : -1;
            s4.z = (e0 + 2 < E) ? src[e0 + 2] : -1;
            s4.w = (e0 + 3 < E) ? dst == src ? -1 : src[e0 + 3] : -1;
            d4.x = (e0 + 0 < E) ? dst[e0 + 0] : -1;
            d4.y = (e0 + 1 < E) ? dst[e0 + 1] : -1;
            d4.z = (e0 + 2 < E) ? dst[e0 + 2] : -1;
            d4.w = (e0 + 3 < E) ? dst[e0 + 3] : -1;
        }
        int ss[4] = { s4.x, s4.y, s4.z, s4.w };
        int dd[4] = { d4.x, d4.y, d4.z, d4.w };
        #pragma unroll
        for (int c = 0; c < 4; ++c) {
            int i = j * 4 + c;
            int b = -1;
            u32 r = 0;
            unsigned d = (unsigned)dd[c], s = (unsigned)ss[c];
            if (d < (unsigned)N && s < (unsigned)N) {
                b = (int)(d / BIN_W);
                r = ((d - (unsigned)b * BIN_W) << 23) | s;
            }
            rec[i] = r;
            mybr[i] = (b >= 0) ? ((b << 16) | atomicAdd(&cnt[b], 1)) : -1;
        }
    }
    __syncthreads();

    // phase B: wave-scan of cnt (exclusive)
    int v = cnt[tid];
    int sv = v;
    #pragma unroll
    for (int d = 1; d < 64; d <<= 1) {
        int tt = __shfl_up(sv, d);
        if (lane >= d) sv += tt;
    }
    if (lane == 63) wsum[wave] = sv;
    __syncthreads();
    if (tid == 0) {
        int a = 0;
        #pragma unroll
        for (int j = 0; j < 4; ++j) { int tt = wsum[j]; wsum[j] = a; a += tt; }
        wsum[4] = a;
    }
    __syncthreads();
    int excl = sv - v + wsum[wave];
    off[tid] = excl;
    if (tid == 0) off[256] = wsum[4];

    dir[t * DIRW + tid] = excl;
    if (tid == 0) dir[t * DIRW + 256] = wsum[4];
    if (v > 0) atomicAdd(&bin_cnt[tid], v);
    __syncthreads();

    // phase C: place records into LDS at binned positions (rank precomputed)
    #pragma unroll
    for (int i = 0; i < EPT; ++i) {
        int br = mybr[i];
        if (br >= 0)
            buf[off[br >> 16] + (br & 0xFFFF)] = rec[i];
    }
    __syncthreads();

    // phase D: sequential coalesced flush
    int total = off[256];
    for (int i = tid; i < total; i += K1_THREADS)
        records[(size_t)base + i] = buf[i];
}

// ---------------- block-wide exclusive scan helper (1024 thr, 2 barriers) ----------------
__device__ __forceinline__ int block_scan_excl(int v, int* wsum, int tid) {
    const int lane = tid & 63, wave = tid >> 6;
    int sv = v;
    #pragma unroll
    for (int d = 1; d < 64; d <<= 1) {
        int tt = __shfl_up(sv, d);
        if (lane >= d) sv += tt;
    }
    if (lane == 63) wsum[wave] = sv;
    __syncthreads();
    if (tid == 0) {
        int a = 0;
        #pragma unroll
        for (int j = 0; j < 16; ++j) { int tt = wsum[j]; wsum[j] = a; a += tt; }
        wsum[16] = a;                       // total
    }
    __syncthreads();
    return sv - v + wsum[wave];
}

// ---------------- K3: per-bin CSR build, one-pass keyed counting sort ----------------
__global__ __launch_bounds__(K3_THREADS)
void csr_build_kernel(const u32* __restrict__ records,
                      const int* __restrict__ dir,
                      const int* __restrict__ bin_cnt,
                      float* __restrict__ dis,
                      int* __restrict__ row_ptr,
                      int* __restrict__ csr_src, int N, int NT, int NB,
                      int bshift) {
    __shared__ u32 ldsrec[CAP];       // 32KB
    __shared__ int cnt2[KMAXP];       // 25KB: histogram, then cursors
    __shared__ int wsum[17];
    __shared__ int sbeg[MAX_NT];
    __shared__ int send[MAX_NT];
    __shared__ int lofs[MAX_NT];
    __shared__ int sh_total, sh_gb0;

    const int b  = blockIdx.x;
    const int lo = b * BIN_W;
    const int nodes = min(BIN_W, N - lo);
    const int tid = threadIdx.x;
    const int wave = tid >> 6, lane = tid & 63;

    // --- bin_base scan ---
    int bv = (tid < NB) ? bin_cnt[tid] : 0;
    int excl = block_scan_excl(bv, wsum, tid);
    if (tid == b) sh_gb0 = excl;
    if (b == 0 && tid == 0) row_ptr[N] = wsum[16];
    __syncthreads();

    // --- run bounds + LDS-offset scan (NT <= K3_THREADS) ---
    int len = 0;
    if (tid < NT) {
        sbeg[tid] = dir[tid * DIRW + b];
        send[tid] = dir[tid * DIRW + b + 1];
        len = send[tid] - sbeg[tid];
    }
    int excl2 = block_scan_excl(len, wsum, tid);
    if (tid < NT) lofs[tid] = excl2;
    if (tid == 0) sh_total = wsum[16];
    __syncthreads();

    const int total = sh_total;
    const bool fits = (total <= CAP);

    // --- copy records into LDS: 2 runs per wave (32 lanes each) ---
    if (fits) {
        for (int rb = wave * 2; rb < NT; rb += 32) {
            int r = rb + (lane >> 5);
            if (r < NT) {
                int g0  = r * TILE + sbeg[r];
                int l0  = lofs[r];
                int ln  = send[r] - sbeg[r];
                for (int k = (lane & 31); k < ln; k += 32)
                    ldsrec[l0 + k] = records[g0 + k];
            }
        }
    }
    __syncthreads();

    // --- keyed histogram: key = dloc*16 + (src>>bshift) ---
    for (int i = tid; i < KMAXP; i += K3_THREADS) cnt2[i] = 0;
    __syncthreads();
    if (fits) {
        for (int i = tid; i < total; i += K3_THREADS) {
            u32 r = ldsrec[i];
            int key = (int)(r >> 23) * NBUCK + (int)((r & 0x7FFFFF) >> bshift);
            atomicAdd(&cnt2[key], 1);
        }
    } else {
        for (int t = wave; t < NT; t += 16) {
            int s = sbeg[t], e = send[t], gb = t * TILE;
            for (int k = s + lane; k < e; k += 64) {
                u32 r = records[gb + k];
                int key = (int)(r >> 23) * NBUCK + (int)((r & 0x7FFFFF) >> bshift);
                atomicAdd(&cnt2[key], 1);
            }
        }
    }
    __syncthreads();

    // --- dis from per-node bucket sums ---
    if (tid < nodes) {
        int c = 0;
        #pragma unroll
        for (int j = 0; j < NBUCK; ++j) c += cnt2[tid * NBUCK + j];
        dis[lo + tid] = (c > 0) ? rsqrtf((float)c) : 0.0f;
    }

    // --- ownership scan over KMAXP keys (KPT per thread) ---
    int base7 = tid * KPT;
    int loc[KPT];
    int s = 0;
    #pragma unroll
    for (int j = 0; j < KPT; ++j) {
        int k = base7 + j;
        loc[j] = s;
        if (k < KMAXP) s += cnt2[k];
    }
    int excl3 = block_scan_excl(s, wsum, tid);
    __syncthreads();
    #pragma unroll
    for (int j = 0; j < KPT; ++j) {
        int k = base7 + j;
        if (k < KMAXP) cnt2[k] = sh_gb0 + excl3 + loc[j];
    }
    __syncthreads();

    // --- row_ptr = cursor of each node's bucket 0 (before scatter mutates) ---
    if (tid < nodes) row_ptr[lo + tid] = cnt2[tid * NBUCK];
    __syncthreads();

    // --- single scatter pass (bucket-sorted rows via key order) ---
    if (fits) {
        for (int i = tid; i < total; i += K3_THREADS) {
            u32 r = ldsrec[i];
            u32 sc = r & 0x7FFFFF;
            int key = (int)(r >> 23) * NBUCK + (int)(sc >> bshift);
            int pos = atomicAdd(&cnt2[key], 1);
            csr_src[pos] = (int)sc;
        }
    } else {
        for (int t = wave; t < NT; t += 16) {
            int s0 = sbeg[t], e0 = send[t], gb = t * TILE;
            for (int k = s0 + lane; k < e0; k += 64) {
                u32 r = records[gb + k];
                u32 sc = r & 0x7FFFFF;
                int key = (int)(r >> 23) * NBUCK + (int)(sc >> bshift);
                int pos = atomicAdd(&cnt2[key], 1);
                csr_src[pos] = (int)sc;
            }
        }
    }
}

// ---------------- K4: stage xs = dis[s] * x[s] -> fp16 (__half2 pairs) ----------------
__global__ __launch_bounds__(256)
void stage_xs_kernel(const float* __restrict__ x, const float* __restrict__ dis,
                     __half2* __restrict__ xs, int total4 /* N*DFEAT/4 */) {
    int i = blockIdx.x * blockDim.x + threadIdx.x;
    if (i < total4) {
        float w = dis[i >> 4];   // 16 float4 per node
        float4 f = *reinterpret_cast<const float4*>(x + (size_t)i * 4);
        xs[i * 2]     = __floats2half2_rn(f.x * w, f.y * w);
        xs[i * 2 + 1] = __floats2half2_rn(f.z * w, f.w * w);
    }
}

// ---------------- K5: gather — 4 nodes/wave, serial src-sorted walk, unroll 8 ----------------
// lane = q*16 + c8: q = node-of-quad (0..3), c8 = 8B column (features 4c8..4c8+3)
struct alignas(8) h4 { __half2 a, b; };

__global__ void gather_s_kernel(const h4* __restrict__ xs4,
                                const int* __restrict__ row_ptr,
                                const int* __restrict__ csr_src,
                                const float* __restrict__ dis,
                                float* __restrict__ out, int N) {
    long long gt = blockIdx.x * (long long)blockDim.x + threadIdx.x;
    int node = (int)((gt >> 6) * 4) + ((threadIdx.x & 63) >> 4);
    int c8 = threadIdx.x & 15;
    if (node >= N) return;
    int beg = row_ptr[node];
    int end = row_ptr[node + 1];
    float a0 = 0.0f, a1 = 0.0f, a2 = 0.0f, a3 = 0.0f;
    int k = beg;
    for (; k + 7 < end; k += 8) {          // 8 sorted lines in flight
        int s0 = __builtin_nontemporal_load(csr_src + k);
        int s1 = __builtin_nontemporal_load(csr_src + k + 1);
        int s2 = __builtin_nontemporal_load(csr_src + k + 2);
        int s3 = __builtin_nontemporal_load(csr_src + k + 3);
        int s4 = __builtin_nontemporal_load(csr_src + k + 4);
        int s5 = __builtin_nontemporal_load(csr_src + k + 5);
        int s6 = __builtin_nontemporal_load(csr_src + k + 6);
        int s7 = __builtin_nontemporal_load(csr_src + k + 7);
        h4 v0 = xs4[(size_t)s0 * 16 + c8];
        h4 v1 = xs4[(size_t)s1 * 16 + c8];
        h4 v2 = xs4[(size_t)s2 * 16 + c8];
        h4 v3 = xs4[(size_t)s3 * 16 + c8];
        h4 v4 = xs4[(size_t)s4 * 16 + c8];
        h4 v5 = xs4[(size_t)s5 * 16 + c8];
        h4 v6 = xs4[(size_t)s6 * 16 + c8];
        h4 v7 = xs4[(size_t)s7 * 16 + c8];
        float2 f0 = __half22float2(v0.a), g0 = __half22float2(v0.b);
        float2 f1 = __half22float2(v1.a), g1 = __half22float2(v1.b);
        float2 f2 = __half22float2(v2.a), g2 = __half22float2(v2.b);
        float2 f3 = __half22float2(v3.a), g3 = __half22float2(v3.b);
        float2 f4 = __half22float2(v4.a), g4 = __half22float2(v4.b);
        float2 f5 = __half22float2(v5.a), g5 = __half22float2(v5.b);
        float2 f6 = __half22float2(v6.a), g6 = __half22float2(v6.b);
        float2 f7 = __half22float2(v7.a), g7 = __half22float2(v7.b);
        a0 += ((f0.x + f1.x) + (f2.x + f3.x)) + ((f4.x + f5.x) + (f6.x + f7.x));
        a1 += ((f0.y + f1.y) + (f2.y + f3.y)) + ((f4.y + f5.y) + (f6.y + f7.y));
        a2 += ((g0.x + g1.x) + (g2.x + g3.x)) + ((g4.x + g5.x) + (g6.x + g7.x));
        a3 += ((g0.y + g1.y) + (g2.y + g3.y)) + ((g4.y + g5.y) + (g6.y + g7.y));
    }
    for (; k + 1 < end; k += 2) {
        int s0 = __builtin_nontemporal_load(csr_src + k);
        int s1 = __builtin_nontemporal_load(csr_src + k + 1);
        h4 v0 = xs4[(size_t)s0 * 16 + c8];
        h4 v1 = xs4[(size_t)s1 * 16 + c8];
        float2 f0 = __half22float2(v0.a), g0 = __half22float2(v0.b);
        float2 f1 = __half22float2(v1.a), g1 = __half22float2(v1.b);
        a0 += f0.x + f1.x; a1 += f0.y + f1.y;
        a2 += g0.x + g1.x; a3 += g0.y + g1.y;
    }
    if (k < end) {
        int s0 = __builtin_nontemporal_load(csr_src + k);
        h4 v0 = xs4[(size_t)s0 * 16 + c8];
        float2 f0 = __half22float2(v0.a), g0 = __half22float2(v0.b);
        a0 += f0.x; a1 += f0.y; a2 += g0.x; a3 += g0.y;
    }
    float dd = dis[node];
    f4v o = { a0 * dd, a1 * dd, a2 * dd, a3 * dd };
    __builtin_nontemporal_store(o, (f4v*)(out + (size_t)node * DFEAT + c8 * 4));
}

// ---------------- fallback (atomic scatter) if ws too small ----------------
__global__ void fb_deg_kernel(const int* __restrict__ dst,
                              float* __restrict__ deg, int E, int N) {
    int e = blockIdx.x * blockDim.x + threadIdx.x;
    if (e < E) {
        unsigned d = (unsigned)dst[e];
        if (d < (unsigned)N) unsafeAtomicAdd(&deg[d], 1.0f);
    }
}
__global__ void fb_dis_kernel(float* __restrict__ deg, int N) {
    int i = blockIdx.x * blockDim.x + threadIdx.x;
    if (i < N) {
        float d = deg[i];
        deg[i] = (d > 0.0f) ? rsqrtf(d) : 0.0f;
    }
}
__global__ void fb_scatter_kernel(const float* __restrict__ x,
                                  const int* __restrict__ src,
                                  const int* __restrict__ dst,
                                  const float* __restrict__ dis,
                                  float* __restrict__ out, int E, int N) {
    long long t = (long long)blockIdx.x * blockDim.x + threadIdx.x;
    int e = (int)(t >> 4);
    int c = (int)(t & 15);
    if (e >= E) return;
    unsigned s = (unsigned)src[e];
    unsigned d = (unsigned)dst[e];
    if (s >= (unsigned)N || d >= (unsigned)N) return;
    float norm = dis[s] * dis[d];
    const float4 v = *reinterpret_cast<const float4*>(x + (size_t)s * DFEAT + c * 4);
    float* o = out + (size_t)d * DFEAT + c * 4;
    unsafeAtomicAdd(o + 0, v.x * norm);
    unsafeAtomicAdd(o + 1, v.y * norm);
    unsafeAtomicAdd(o + 2, v.z * norm);
    unsafeAtomicAdd(o + 3, v.w * norm);
}

extern "C" void kernel_launch(void* const* d_in, const int* in_sizes, int n_in,
                              void* d_out, int out_size, void* d_ws, size_t ws_size,
                              hipStream_t stream) {
    const float* x  = (const float*)d_in[0];
    const int*   ei = (const int*)d_in[1];   // harness delivers integer inputs as int32

    const int N = in_sizes[0] / DFEAT;        // 100000
    const int E = in_sizes[1] / 2;            // 1600000
    const int* src = ei;                      // row 0
    const int* dst = ei + E;                  // row 1

    float* out = (float*)d_out;

    const int NB = (N + BIN_W - 1) / BIN_W;   // bins (256 for N=100000)
    const int NT = (E + TILE - 1) / TILE;     // tiles (196 for E=1.6M)

    // src bucket shift: <= NBUCK buckets over [0,N)
    int bshift = 13;
    while ((((N - 1) >> bshift) + 1) > NBUCK) bshift++;

    // workspace layout (16B-aligned chunks)
    char* base = (char*)d_ws;
    size_t off = 0;
    auto alloc = [&](size_t bytes) { void* p = base + off; off += (bytes + 15) & ~(size_t)15; return p; };
    size_t rec_bytes = (size_t)NT * TILE * 4;
    size_t xs_bytes  = (size_t)N * DFEAT * 2;
    size_t region    = rec_bytes > xs_bytes ? rec_bytes : xs_bytes;
    u32*   records  = (u32*)alloc(region);    // records, later overlaid by xs
    int*   dir      = (int*)alloc((size_t)NT * DIRW * 4);
    int*   bin_cnt  = (int*)alloc(256 * 4);
    float* dis      = (float*)alloc((size_t)N * 4);
    int*   row_ptr  = (int*)alloc((size_t)(N + 1) * 4);
    int*   csr_src  = (int*)alloc((size_t)E * 4);

    const bool ok = (off <= ws_size) && (NB <= 256) && (NT <= MAX_NT) &&
                    (NT <= K3_THREADS) && (N <= (1 << 23)) && (BIN_W <= 512);

    if (ok) {
        hipMemsetAsync(bin_cnt, 0, 256 * 4, stream);

        bin_kernel<<<NT, K1_THREADS, 0, stream>>>(src, dst, records, dir, bin_cnt, E, N);
        csr_build_kernel<<<NB, K3_THREADS, 0, stream>>>(records, dir, bin_cnt, dis,
                                                        row_ptr, csr_src, N, NT, NB,
                                                        bshift);

        __half2* xs = (__half2*)records;      // overlay: records dead after K3
        int total4 = N * DFEAT / 4;
        stage_xs_kernel<<<(total4 + 255) / 256, 256, 0, stream>>>(x, dis, xs, total4);

        // 16 nodes per 256-thread block (4 nodes per wave)
        int gblocks = (N + 15) / 16;
        gather_s_kernel<<<gblocks, 256, 0, stream>>>((const h4*)xs, row_ptr, csr_src, dis, out, N);
    } else {
        // fallback: atomic scatter (needs only N floats of ws)
        float* deg = (float*)d_ws;
        hipMemsetAsync(deg, 0, (size_t)N * 4, stream);
        hipMemsetAsync(out, 0, (size_t)out_size * 4, stream);
        int eb = (E + 255) / 256;
        fb_deg_kernel<<<eb, 256, 0, stream>>>(dst, deg, E, N);
        int nb = (N + 255) / 256;
        fb_dis_kernel<<<nb, 256, 0, stream>>>(deg, N);
        long long total = (long long)E * 16;
        int sb = (int)((total + 255) / 256);
        fb_scatter_kernel<<<sb, 256, 0, stream>>>(x, src, dst, deg, out, E, N);
    }
}

// Round 18
// 85.772 us; speedup vs baseline: 7.7925x; 1.0080x over previous
//
#include <hip/hip_runtime.h>
#include <hip/hip_fp16.h>

// LGConv: out = D^{-1/2} A D^{-1/2} x
// x: f32 [N, 64]; edge_index: int32 on device (harness downcasts int64), [2, E]
//
// Pipeline:
//  K0 zero_kernel: zero bin_cnt (replaces hipMemsetAsync blit).
//  K1 bin_kernel: per 8192-edge tile, LDS count(+rank)/scan/reorder by
//     dst-bin, sequential flush of packed 4B records ((dloc<<23)|src) +
//     directory. int4 edge loads, single LDS atomic per edge, wave-scan.
//  K3 csr_build: one block per bin; records in LDS once; single-pass
//     (node,bucket)-keyed counting sort -> dis, row_ptr, bucket-sorted rows.
//     If xs buffer is separate (Path A), also stages xs = dis*x fp16 for its
//     own nodes (fused stage, one fewer dispatch).
//  K4 stage_xs (Path B only): xs overlaid on dead records region.
//  K5 gather_s: 4 nodes/wave, 16 lanes/node (8B col each); serial sorted
//     walk, unroll 8 (8 lines in flight), nontemporal csr, float4 store.

#define DFEAT 64
#define BIN_W 391          // nodes per bin; NB = ceil(N/BIN_W) must be <= 256
#define TILE 8192          // edges per K1 block
#define K1_THREADS 256
#define EPT (TILE / K1_THREADS)   // 32
#define DIRW 257
#define K3_THREADS 1024
#define MAX_NT 512         // NT must be <= this (and <= K3_THREADS)
#define CAP 8192           // LDS record capacity (mean 6250, +24 sigma)
#define NBUCK 16
#define KMAXP (BIN_W * NBUCK)            // 6256 keys
#define KPT ((KMAXP + K3_THREADS - 1) / K3_THREADS)  // 7 keys per thread

typedef unsigned long long u64;
typedef unsigned int u32;
typedef float f4v __attribute__((ext_vector_type(4)));

struct alignas(8) h4 { __half2 a, b; };   // 4 fp16 features

// ---------------- K0: zero bin_cnt ----------------
__global__ void zero_kernel(int* __restrict__ p, int n) {
    int i = blockIdx.x * blockDim.x + threadIdx.x;
    if (i < n) p[i] = 0;
}

// ---------------- K1: LDS-reordered binning, packed 4B records ----------------
__global__ __launch_bounds__(K1_THREADS)
void bin_kernel(const int* __restrict__ src, const int* __restrict__ dst,
                u32* __restrict__ records, int* __restrict__ dir,
                int* __restrict__ bin_cnt, int E, int N) {
    __shared__ int cnt[256];
    __shared__ int off[DIRW];
    __shared__ int wsum[5];
    __shared__ u32 buf[TILE];

    const int t    = blockIdx.x;
    const int base = t * TILE;
    const int tid  = threadIdx.x;
    const int lane = tid & 63, wave = tid >> 6;

    cnt[tid] = 0;
    __syncthreads();

    // phase A: vectorized load + count-with-rank (one LDS atomic per edge)
    u32 rec[EPT];
    int mybr[EPT];                  // (bin<<16)|rank, or -1
    #pragma unroll
    for (int j = 0; j < EPT / 4; ++j) {
        int e0 = base + 4 * (tid + j * K1_THREADS);
        int4 s4, d4;
        if (e0 + 3 < E) {
            s4 = *reinterpret_cast<const int4*>(src + e0);
            d4 = *reinterpret_cast<const int4*>(dst + e0);
        } else {
            s4.x = (e0 + 0 < E) ? src[e0 + 0] : -1;
            s4.y = (e0 + 1 < E) ? src[e0 + 1] : -1;
            s4.z = (e0 + 2 < E) ? src[e0 + 2] : -1;
            s4.w = (e0 + 3 < E) ? src[e0 + 3] : -1;
            d4.x = (e0 + 0 < E) ? dst[e0 + 0] : -1;
            d4.y = (e0 + 1 < E) ? dst[e0 + 1] : -1;
            d4.z = (e0 + 2 < E) ? dst[e0 + 2] : -1;
            d4.w = (e0 + 3 < E) ? dst[e0 + 3] : -1;
        }
        int ss[4] = { s4.x, s4.y, s4.z, s4.w };
        int dd[4] = { d4.x, d4.y, d4.z, d4.w };
        #pragma unroll
        for (int c = 0; c < 4; ++c) {
            int i = j * 4 + c;
            int b = -1;
            u32 r = 0;
            unsigned d = (unsigned)dd[c], s = (unsigned)ss[c];
            if (d < (unsigned)N && s < (unsigned)N) {
                b = (int)(d / BIN_W);
                r = ((d - (unsigned)b * BIN_W) << 23) | s;
            }
            rec[i] = r;
            mybr[i] = (b >= 0) ? ((b << 16) | atomicAdd(&cnt[b], 1)) : -1;
        }
    }
    __syncthreads();

    // phase B: wave-scan of cnt (exclusive)
    int v = cnt[tid];
    int sv = v;
    #pragma unroll
    for (int d = 1; d < 64; d <<= 1) {
        int tt = __shfl_up(sv, d);
        if (lane >= d) sv += tt;
    }
    if (lane == 63) wsum[wave] = sv;
    __syncthreads();
    if (tid == 0) {
        int a = 0;
        #pragma unroll
        for (int j = 0; j < 4; ++j) { int tt = wsum[j]; wsum[j] = a; a += tt; }
        wsum[4] = a;
    }
    __syncthreads();
    int excl = sv - v + wsum[wave];
    off[tid] = excl;
    if (tid == 0) off[256] = wsum[4];

    dir[t * DIRW + tid] = excl;
    if (tid == 0) dir[t * DIRW + 256] = wsum[4];
    if (v > 0) atomicAdd(&bin_cnt[tid], v);
    __syncthreads();

    // phase C: place records into LDS at binned positions (rank precomputed)
    #pragma unroll
    for (int i = 0; i < EPT; ++i) {
        int br = mybr[i];
        if (br >= 0)
            buf[off[br >> 16] + (br & 0xFFFF)] = rec[i];
    }
    __syncthreads();

    // phase D: sequential coalesced flush
    int total = off[256];
    for (int i = tid; i < total; i += K1_THREADS)
        records[(size_t)base + i] = buf[i];
}

// ---------------- block-wide exclusive scan helper (1024 thr, 2 barriers) ----------------
__device__ __forceinline__ int block_scan_excl(int v, int* wsum, int tid) {
    const int lane = tid & 63, wave = tid >> 6;
    int sv = v;
    #pragma unroll
    for (int d = 1; d < 64; d <<= 1) {
        int tt = __shfl_up(sv, d);
        if (lane >= d) sv += tt;
    }
    if (lane == 63) wsum[wave] = sv;
    __syncthreads();
    if (tid == 0) {
        int a = 0;
        #pragma unroll
        for (int j = 0; j < 16; ++j) { int tt = wsum[j]; wsum[j] = a; a += tt; }
        wsum[16] = a;                       // total
    }
    __syncthreads();
    return sv - v + wsum[wave];
}

// ---------------- K3: per-bin CSR build (+ optional fused xs staging) ----------------
__global__ __launch_bounds__(K3_THREADS)
void csr_build_kernel(const u32* __restrict__ records,
                      const int* __restrict__ dir,
                      const int* __restrict__ bin_cnt,
                      float* __restrict__ dis,
                      int* __restrict__ row_ptr,
                      int* __restrict__ csr_src,
                      const float* __restrict__ x,   // for fused staging
                      h4* __restrict__ xs,           // nullptr -> no staging
                      int N, int NT, int NB, int bshift) {
    __shared__ u32 ldsrec[CAP];       // 32KB
    __shared__ int cnt2[KMAXP];       // 25KB: histogram, then cursors
    __shared__ float disl[BIN_W];     // dis values for fused staging
    __shared__ int wsum[17];
    __shared__ int sbeg[MAX_NT];
    __shared__ int send[MAX_NT];
    __shared__ int lofs[MAX_NT];
    __shared__ int sh_total, sh_gb0;

    const int b  = blockIdx.x;
    const int lo = b * BIN_W;
    const int nodes = min(BIN_W, N - lo);
    const int tid = threadIdx.x;
    const int wave = tid >> 6, lane = tid & 63;

    // --- bin_base scan ---
    int bv = (tid < NB) ? bin_cnt[tid] : 0;
    int excl = block_scan_excl(bv, wsum, tid);
    if (tid == b) sh_gb0 = excl;
    if (b == 0 && tid == 0) row_ptr[N] = wsum[16];
    __syncthreads();

    // --- run bounds + LDS-offset scan (NT <= K3_THREADS) ---
    int len = 0;
    if (tid < NT) {
        sbeg[tid] = dir[tid * DIRW + b];
        send[tid] = dir[tid * DIRW + b + 1];
        len = send[tid] - sbeg[tid];
    }
    int excl2 = block_scan_excl(len, wsum, tid);
    if (tid < NT) lofs[tid] = excl2;
    if (tid == 0) sh_total = wsum[16];
    __syncthreads();

    const int total = sh_total;
    const bool fits = (total <= CAP);

    // --- copy records into LDS: 2 runs per wave (32 lanes each) ---
    if (fits) {
        for (int rb = wave * 2; rb < NT; rb += 32) {
            int r = rb + (lane >> 5);
            if (r < NT) {
                int g0  = r * TILE + sbeg[r];
                int l0  = lofs[r];
                int ln  = send[r] - sbeg[r];
                for (int k = (lane & 31); k < ln; k += 32)
                    ldsrec[l0 + k] = records[g0 + k];
            }
        }
    }
    __syncthreads();

    // --- keyed histogram: key = dloc*16 + (src>>bshift) ---
    for (int i = tid; i < KMAXP; i += K3_THREADS) cnt2[i] = 0;
    __syncthreads();
    if (fits) {
        for (int i = tid; i < total; i += K3_THREADS) {
            u32 r = ldsrec[i];
            int key = (int)(r >> 23) * NBUCK + (int)((r & 0x7FFFFF) >> bshift);
            atomicAdd(&cnt2[key], 1);
        }
    } else {
        for (int t = wave; t < NT; t += 16) {
            int s = sbeg[t], e = send[t], gb = t * TILE;
            for (int k = s + lane; k < e; k += 64) {
                u32 r = records[gb + k];
                int key = (int)(r >> 23) * NBUCK + (int)((r & 0x7FFFFF) >> bshift);
                atomicAdd(&cnt2[key], 1);
            }
        }
    }
    __syncthreads();

    // --- dis from per-node bucket sums ---
    if (tid < nodes) {
        int c = 0;
        #pragma unroll
        for (int j = 0; j < NBUCK; ++j) c += cnt2[tid * NBUCK + j];
        float w = (c > 0) ? rsqrtf((float)c) : 0.0f;
        dis[lo + tid] = w;
        disl[tid] = w;
    }

    // --- ownership scan over KMAXP keys (KPT per thread) ---
    int base7 = tid * KPT;
    int loc[KPT];
    int s = 0;
    #pragma unroll
    for (int j = 0; j < KPT; ++j) {
        int k = base7 + j;
        loc[j] = s;
        if (k < KMAXP) s += cnt2[k];
    }
    int excl3 = block_scan_excl(s, wsum, tid);
    __syncthreads();
    #pragma unroll
    for (int j = 0; j < KPT; ++j) {
        int k = base7 + j;
        if (k < KMAXP) cnt2[k] = sh_gb0 + excl3 + loc[j];
    }
    __syncthreads();

    // --- row_ptr = cursor of each node's bucket 0 (before scatter mutates) ---
    if (tid < nodes) row_ptr[lo + tid] = cnt2[tid * NBUCK];
    __syncthreads();

    // --- single scatter pass (bucket-sorted rows via key order) ---
    if (fits) {
        for (int i = tid; i < total; i += K3_THREADS) {
            u32 r = ldsrec[i];
            u32 sc = r & 0x7FFFFF;
            int key = (int)(r >> 23) * NBUCK + (int)(sc >> bshift);
            int pos = atomicAdd(&cnt2[key], 1);
            csr_src[pos] = (int)sc;
        }
    } else {
        for (int t = wave; t < NT; t += 16) {
            int s0 = sbeg[t], e0 = send[t], gb = t * TILE;
            for (int k = s0 + lane; k < e0; k += 64) {
                u32 r = records[gb + k];
                u32 sc = r & 0x7FFFFF;
                int key = (int)(r >> 23) * NBUCK + (int)(sc >> bshift);
                int pos = atomicAdd(&cnt2[key], 1);
                csr_src[pos] = (int)sc;
            }
        }
    }

    // --- fused xs staging for this bin's nodes (Path A) ---
    if (xs != nullptr) {
        const f4v* x4 = reinterpret_cast<const f4v*>(x);
        for (int i = tid; i < nodes * 16; i += K3_THREADS) {
            int nl = i >> 4;
            int c  = i & 15;
            float w = disl[nl];
            f4v f = __builtin_nontemporal_load(x4 + (size_t)(lo + nl) * 16 + c);
            h4 o;
            o.a = __floats2half2_rn(f.x * w, f.y * w);
            o.b = __floats2half2_rn(f.z * w, f.w * w);
            xs[(size_t)(lo + nl) * 16 + c] = o;
        }
    }
}

// ---------------- K4 (Path B): stage xs = dis[s] * x[s] -> fp16 ----------------
__global__ __launch_bounds__(256)
void stage_xs_kernel(const float* __restrict__ x, const float* __restrict__ dis,
                     __half2* __restrict__ xs, int total4 /* N*DFEAT/4 */) {
    int i = blockIdx.x * blockDim.x + threadIdx.x;
    if (i < total4) {
        float w = dis[i >> 4];   // 16 float4 per node
        float4 f = *reinterpret_cast<const float4*>(x + (size_t)i * 4);
        xs[i * 2]     = __floats2half2_rn(f.x * w, f.y * w);
        xs[i * 2 + 1] = __floats2half2_rn(f.z * w, f.w * w);
    }
}

// ---------------- K5: gather — 4 nodes/wave, serial src-sorted walk, unroll 8 ----------------
__global__ void gather_s_kernel(const h4* __restrict__ xs4,
                                const int* __restrict__ row_ptr,
                                const int* __restrict__ csr_src,
                                const float* __restrict__ dis,
                                float* __restrict__ out, int N) {
    long long gt = blockIdx.x * (long long)blockDim.x + threadIdx.x;
    int node = (int)((gt >> 6) * 4) + ((threadIdx.x & 63) >> 4);
    int c8 = threadIdx.x & 15;
    if (node >= N) return;
    int beg = row_ptr[node];
    int end = row_ptr[node + 1];
    float a0 = 0.0f, a1 = 0.0f, a2 = 0.0f, a3 = 0.0f;
    int k = beg;
    for (; k + 7 < end; k += 8) {          // 8 sorted lines in flight
        int s0 = __builtin_nontemporal_load(csr_src + k);
        int s1 = __builtin_nontemporal_load(csr_src + k + 1);
        int s2 = __builtin_nontemporal_load(csr_src + k + 2);
        int s3 = __builtin_nontemporal_load(csr_src + k + 3);
        int s4 = __builtin_nontemporal_load(csr_src + k + 4);
        int s5 = __builtin_nontemporal_load(csr_src + k + 5);
        int s6 = __builtin_nontemporal_load(csr_src + k + 6);
        int s7 = __builtin_nontemporal_load(csr_src + k + 7);
        h4 v0 = xs4[(size_t)s0 * 16 + c8];
        h4 v1 = xs4[(size_t)s1 * 16 + c8];
        h4 v2 = xs4[(size_t)s2 * 16 + c8];
        h4 v3 = xs4[(size_t)s3 * 16 + c8];
        h4 v4 = xs4[(size_t)s4 * 16 + c8];
        h4 v5 = xs4[(size_t)s5 * 16 + c8];
        h4 v6 = xs4[(size_t)s6 * 16 + c8];
        h4 v7 = xs4[(size_t)s7 * 16 + c8];
        float2 f0 = __half22float2(v0.a), g0 = __half22float2(v0.b);
        float2 f1 = __half22float2(v1.a), g1 = __half22float2(v1.b);
        float2 f2 = __half22float2(v2.a), g2 = __half22float2(v2.b);
        float2 f3 = __half22float2(v3.a), g3 = __half22float2(v3.b);
        float2 f4 = __half22float2(v4.a), g4 = __half22float2(v4.b);
        float2 f5 = __half22float2(v5.a), g5 = __half22float2(v5.b);
        float2 f6 = __half22float2(v6.a), g6 = __half22float2(v6.b);
        float2 f7 = __half22float2(v7.a), g7 = __half22float2(v7.b);
        a0 += ((f0.x + f1.x) + (f2.x + f3.x)) + ((f4.x + f5.x) + (f6.x + f7.x));
        a1 += ((f0.y + f1.y) + (f2.y + f3.y)) + ((f4.y + f5.y) + (f6.y + f7.y));
        a2 += ((g0.x + g1.x) + (g2.x + g3.x)) + ((g4.x + g5.x) + (g6.x + g7.x));
        a3 += ((g0.y + g1.y) + (g2.y + g3.y)) + ((g4.y + g5.y) + (g6.y + g7.y));
    }
    for (; k + 1 < end; k += 2) {
        int s0 = __builtin_nontemporal_load(csr_src + k);
        int s1 = __builtin_nontemporal_load(csr_src + k + 1);
        h4 v0 = xs4[(size_t)s0 * 16 + c8];
        h4 v1 = xs4[(size_t)s1 * 16 + c8];
        float2 f0 = __half22float2(v0.a), g0 = __half22float2(v0.b);
        float2 f1 = __half22float2(v1.a), g1 = __half22float2(v1.b);
        a0 += f0.x + f1.x; a1 += f0.y + f1.y;
        a2 += g0.x + g1.x; a3 += g0.y + g1.y;
    }
    if (k < end) {
        int s0 = __builtin_nontemporal_load(csr_src + k);
        h4 v0 = xs4[(size_t)s0 * 16 + c8];
        float2 f0 = __half22float2(v0.a), g0 = __half22float2(v0.b);
        a0 += f0.x; a1 += f0.y; a2 += g0.x; a3 += g0.y;
    }
    float dd = dis[node];
    f4v o = { a0 * dd, a1 * dd, a2 * dd, a3 * dd };
    __builtin_nontemporal_store(o, (f4v*)(out + (size_t)node * DFEAT + c8 * 4));
}

// ---------------- fallback (atomic scatter) if ws too small ----------------
__global__ void fb_deg_kernel(const int* __restrict__ dst,
                              float* __restrict__ deg, int E, int N) {
    int e = blockIdx.x * blockDim.x + threadIdx.x;
    if (e < E) {
        unsigned d = (unsigned)dst[e];
        if (d < (unsigned)N) unsafeAtomicAdd(&deg[d], 1.0f);
    }
}
__global__ void fb_dis_kernel(float* __restrict__ deg, int N) {
    int i = blockIdx.x * blockDim.x + threadIdx.x;
    if (i < N) {
        float d = deg[i];
        deg[i] = (d > 0.0f) ? rsqrtf(d) : 0.0f;
    }
}
__global__ void fb_scatter_kernel(const float* __restrict__ x,
                                  const int* __restrict__ src,
                                  const int* __restrict__ dst,
                                  const float* __restrict__ dis,
                                  float* __restrict__ out, int E, int N) {
    long long t = (long long)blockIdx.x * blockDim.x + threadIdx.x;
    int e = (int)(t >> 4);
    int c = (int)(t & 15);
    if (e >= E) return;
    unsigned s = (unsigned)src[e];
    unsigned d = (unsigned)dst[e];
    if (s >= (unsigned)N || d >= (unsigned)N) return;
    float norm = dis[s] * dis[d];
    const float4 v = *reinterpret_cast<const float4*>(x + (size_t)s * DFEAT + c * 4);
    float* o = out + (size_t)d * DFEAT + c * 4;
    unsafeAtomicAdd(o + 0, v.x * norm);
    unsafeAtomicAdd(o + 1, v.y * norm);
    unsafeAtomicAdd(o + 2, v.z * norm);
    unsafeAtomicAdd(o + 3, v.w * norm);
}

extern "C" void kernel_launch(void* const* d_in, const int* in_sizes, int n_in,
                              void* d_out, int out_size, void* d_ws, size_t ws_size,
                              hipStream_t stream) {
    const float* x  = (const float*)d_in[0];
    const int*   ei = (const int*)d_in[1];   // harness delivers integer inputs as int32

    const int N = in_sizes[0] / DFEAT;        // 100000
    const int E = in_sizes[1] / 2;            // 1600000
    const int* src = ei;                      // row 0
    const int* dst = ei + E;                  // row 1

    float* out = (float*)d_out;

    const int NB = (N + BIN_W - 1) / BIN_W;   // bins (256 for N=100000)
    const int NT = (E + TILE - 1) / TILE;     // tiles (196 for E=1.6M)

    // src bucket shift: <= NBUCK buckets over [0,N)
    int bshift = 13;
    while ((((N - 1) >> bshift) + 1) > NBUCK) bshift++;

    const size_t rec_bytes = (size_t)NT * TILE * 4;
    const size_t xs_bytes  = (size_t)N * DFEAT * 2;
    auto align16 = [](size_t v) { return (v + 15) & ~(size_t)15; };

    // Path A layout (xs separate, fused staging):
    size_t szA = align16(rec_bytes) + align16(xs_bytes);
    // Path B layout (xs overlays records):
    size_t szB = align16(rec_bytes > xs_bytes ? rec_bytes : xs_bytes);
    size_t tail = align16((size_t)NT * DIRW * 4) + align16(256 * 4) +
                  align16((size_t)N * 4) + align16((size_t)(N + 1) * 4) +
                  align16((size_t)E * 4);
    szA += tail; szB += tail;

    const bool structural = (NB <= 256) && (NT <= MAX_NT) && (NT <= K3_THREADS) &&
                            (N <= (1 << 23)) && (BIN_W <= 512);
    const bool pathA = structural && (szA <= ws_size);
    const bool pathB = structural && !pathA && (szB <= ws_size) &&
                       (rec_bytes <= szB - tail) && (xs_bytes <= szB - tail);

    if (pathA || pathB) {
        char* base = (char*)d_ws;
        size_t off = 0;
        auto alloc = [&](size_t bytes) { void* p = base + off; off += align16(bytes); return p; };

        u32* records; h4* xsA = nullptr; __half2* xsB = nullptr;
        if (pathA) {
            records = (u32*)alloc(rec_bytes);
            xsA     = (h4*)alloc(xs_bytes);
        } else {
            records = (u32*)alloc(rec_bytes > xs_bytes ? rec_bytes : xs_bytes);
            xsB     = (__half2*)records;       // overlay; records dead after K3
        }
        int*   dir      = (int*)alloc((size_t)NT * DIRW * 4);
        int*   bin_cnt  = (int*)alloc(256 * 4);
        float* dis      = (float*)alloc((size_t)N * 4);
        int*   row_ptr  = (int*)alloc((size_t)(N + 1) * 4);
        int*   csr_src  = (int*)alloc((size_t)E * 4);

        zero_kernel<<<1, 256, 0, stream>>>(bin_cnt, 256);
        bin_kernel<<<NT, K1_THREADS, 0, stream>>>(src, dst, records, dir, bin_cnt, E, N);
        csr_build_kernel<<<NB, K3_THREADS, 0, stream>>>(records, dir, bin_cnt, dis,
                                                        row_ptr, csr_src, x, xsA,
                                                        N, NT, NB, bshift);
        const h4* xs_final;
        if (pathA) {
            xs_final = xsA;
        } else {
            int total4 = N * DFEAT / 4;
            stage_xs_kernel<<<(total4 + 255) / 256, 256, 0, stream>>>(x, dis, xsB, total4);
            xs_final = (const h4*)xsB;
        }

        int gblocks = (N + 15) / 16;   // 16 nodes per 256-thread block
        gather_s_kernel<<<gblocks, 256, 0, stream>>>(xs_final, row_ptr, csr_src, dis, out, N);
    } else {
        // fallback: atomic scatter (needs only N floats of ws)
        float* deg = (float*)d_ws;
        hipMemsetAsync(deg, 0, (size_t)N * 4, stream);
        hipMemsetAsync(out, 0, (size_t)out_size * 4, stream);
        int eb = (E + 255) / 256;
        fb_deg_kernel<<<eb, 256, 0, stream>>>(dst, deg, E, N);
        int nb = (N + 255) / 256;
        fb_dis_kernel<<<nb, 256, 0, stream>>>(deg, N);
        long long total = (long long)E * 16;
        int sb = (int)((total + 255) / 256);
        fb_scatter_kernel<<<sb, 256, 0, stream>>>(x, src, dst, deg, out, E, N);
    }
}